// Round 5
// baseline (645.301 us; speedup 1.0000x reference)
//
#include <hip/hip_runtime.h>
#include <hip/hip_bf16.h>

typedef __hip_bfloat16 bf16;
typedef unsigned short u16;
typedef unsigned int u32;

#define NS_N 50000
#define ND_N 50000
#define NE_E 600000
#define C 64
#define AD 16
#define SD 64
#define NH 8
#define MF 192
#define EPSV 1e-5f

#define WB() __builtin_amdgcn_wave_barrier()

typedef short short8 __attribute__((ext_vector_type(8)));
typedef float f32x4 __attribute__((ext_vector_type(4)));
#define MFMA16(a, b, c) __builtin_amdgcn_mfma_f32_16x16x32_bf16(a, b, c, 0, 0, 0)

__device__ __forceinline__ float lo16(u32 u) {
    union { u32 i; float f; } v; v.i = u << 16; return v.f;
}
__device__ __forceinline__ float hi16(u32 u) {
    union { u32 i; float f; } v; v.i = u & 0xffff0000u; return v.f;
}
__device__ __forceinline__ float b2fu(u16 u) {
    union { u32 i; float f; } v; v.i = ((u32)u) << 16; return v.f;
}
__device__ __forceinline__ u16 f2bbits(float f) {   // RNE fp32->bf16 bits
    u32 u = __float_as_uint(f);
    u32 r = u + 0x7FFFu + ((u >> 16) & 1u);
    return (u16)(r >> 16);
}
// dtype-adaptive loads: isbf==1 -> buffer is bf16, else fp32
__device__ __forceinline__ float loadf(const void* p, size_t i, int isbf) {
    if (isbf) { union { u32 u; float f; } v; v.u = ((u32)((const u16*)p)[i]) << 16; return v.f; }
    return ((const float*)p)[i];
}
__device__ __forceinline__ u16 loadb(const void* p, size_t i, int isbf) {
    if (isbf) return ((const u16*)p)[i];
    return f2bbits(((const float*)p)[i]);
}
__device__ __forceinline__ short8 load8bf(const void* p, size_t off, int isbf) {
    if (isbf) return *(const short8*)((const u16*)p + off);
    const float4* q = (const float4*)((const float*)p + off);
    float4 f0 = q[0], f1 = q[1];
    short8 r;
    r[0] = (short)f2bbits(f0.x); r[1] = (short)f2bbits(f0.y);
    r[2] = (short)f2bbits(f0.z); r[3] = (short)f2bbits(f0.w);
    r[4] = (short)f2bbits(f1.x); r[5] = (short)f2bbits(f1.y);
    r[6] = (short)f2bbits(f1.z); r[7] = (short)f2bbits(f1.w);
    return r;
}

__device__ __forceinline__ float waveAllSum(float v) {
    #pragma unroll
    for (int off = 32; off >= 1; off >>= 1) v += __shfl_xor(v, off, 64);
    return v;
}

// ================= dtype detection + cnt zero (fused) =================
__global__ void detect_zero_kernel(const void* src, int* flag, int* cnt) {
    if (blockIdx.x == 0) {
        if (threadIdx.x < 64) {
            const u16* p = (const u16*)src;
            const int lane = threadIdx.x;
            int c = 0;
            #pragma unroll
            for (int j = 0; j < 32; ++j) {
                u16 w = p[(size_t)(lane * 32 + j) * 2];
                int e = (w >> 7) & 0xFF;
                if (w == 0 || (e >= 100 && e <= 150)) c++;
            }
            #pragma unroll
            for (int off = 32; off >= 1; off >>= 1) c += __shfl_xor(c, off, 64);
            if (lane == 0) *flag = (c > 1536) ? 1 : 0;
        }
    } else {
        int i = (blockIdx.x - 1) * blockDim.x + threadIdx.x;
        if (i < ND_N) cnt[i] = 0;
    }
}

// ================= CSR build =================
__global__ void hist_kernel(const int* __restrict__ edge_dst, int* __restrict__ cnt) {
    int e = blockIdx.x * blockDim.x + threadIdx.x;
    if (e < NE_E) atomicAdd(&cnt[edge_dst[e]], 1);
}

// ---- 2-phase parallel scan (chunk sums -> per-chunk scan w/ inline chunk-prefix) ----
#define SCAN_CHUNK 1024
#define SCAN_NCH ((ND_N + SCAN_CHUNK - 1) / SCAN_CHUNK)   // 49 (must be <= 64)

__global__ void scan_phase1(const int* __restrict__ cnt, int* __restrict__ chunksum) {
    __shared__ int wsum[4];
    const int b = blockIdx.x, tidx = threadIdx.x;    // 256 threads
    const int base = b * SCAN_CHUNK + tidx * 4;
    int s = 0;
    if (base + 3 < ND_N) {
        int4 v = *(const int4*)&cnt[base];
        s = v.x + v.y + v.z + v.w;
    } else {
        #pragma unroll
        for (int j = 0; j < 4; ++j) { int i = base + j; if (i < ND_N) s += cnt[i]; }
    }
    #pragma unroll
    for (int off = 32; off >= 1; off >>= 1) s += __shfl_xor(s, off, 64);
    const int wv = tidx >> 6, lane = tidx & 63;
    if (lane == 0) wsum[wv] = s;
    __syncthreads();
    if (tidx == 0) chunksum[b] = wsum[0] + wsum[1] + wsum[2] + wsum[3];
}

// phase3 with inlined chunk-offset scan (first wave recomputes the 49-entry prefix)
__global__ void scan_phase3(const int* __restrict__ cnt, const int* __restrict__ chunksum,
                            int* __restrict__ row_ptr, int* __restrict__ cursor,
                            int* __restrict__ row_ptr_last) {
    __shared__ int woff[4];
    __shared__ int choff_s;
    const int b = blockIdx.x, tidx = threadIdx.x;    // 256 threads
    if (tidx < 64) {
        int v = (tidx < SCAN_NCH) ? chunksum[tidx] : 0;
        int incl = v;
        #pragma unroll
        for (int off = 1; off < 64; off <<= 1) {
            int t = __shfl_up(incl, off, 64);
            if (tidx >= off) incl += t;
        }
        if (tidx == b) choff_s = incl - v;           // exclusive prefix for this chunk
        if (b == 0 && tidx == 63) *row_ptr_last = incl;  // grand total
    }
    const int base = b * SCAN_CHUNK + tidx * 4;
    int v[4];
    #pragma unroll
    for (int j = 0; j < 4; ++j) { int i = base + j; v[j] = (i < ND_N) ? cnt[i] : 0; }
    int s = v[0] + v[1] + v[2] + v[3];
    int incl = s;
    const int lane = tidx & 63, wv = tidx >> 6;
    #pragma unroll
    for (int off = 1; off < 64; off <<= 1) {
        int t = __shfl_up(incl, off, 64);
        if (lane >= off) incl += t;
    }
    if (lane == 63) woff[wv] = incl;
    __syncthreads();
    int cross = 0;
    for (int w = 0; w < wv; ++w) cross += woff[w];
    int run = choff_s + cross + (incl - s);
    #pragma unroll
    for (int j = 0; j < 4; ++j) {
        int i = base + j;
        if (i < ND_N) { row_ptr[i] = run; cursor[i] = run; }
        run += v[j];
    }
}

__global__ void scatter_kernel(const int* __restrict__ edge_dst, int* __restrict__ cursor,
                               int* __restrict__ perm) {
    int e = blockIdx.x * blockDim.x + threadIdx.x;
    if (e < NE_E) {
        int pos = atomicAdd(&cursor[edge_dst[e]], 1);
        perm[pos] = e;
    }
}

// ================= fused dual LayerNorm + GEMM (64->64), bf16 output =================
__global__ void node_proj2_kernel(const void* __restrict__ src_f, const void* __restrict__ dst_f,
                                  const void* __restrict__ lnw_s, const void* __restrict__ lnb_s,
                                  const void* __restrict__ W_s,
                                  const void* __restrict__ lnw_d, const void* __restrict__ lnb_d,
                                  const void* __restrict__ W_d, const void* __restrict__ b_d,
                                  const int* __restrict__ flagp,
                                  u16* __restrict__ ms, u16* __restrict__ md) {
    __shared__ u16 sW[C * C];          // packed: (k>>1)*128 + c*2 + (k&1)
    __shared__ float slnw[C], slnb[C], sbias[C];
    __shared__ float ybuf[4][C];

    const int isbf = *flagp;
    const int tid = threadIdx.x;
    const int half = gridDim.x >> 1;
    const int isrc = (blockIdx.x < half) ? 1 : 0;
    const void* xf  = isrc ? src_f : dst_f;
    const void* lnw = isrc ? lnw_s : lnw_d;
    const void* lnb = isrc ? lnb_s : lnb_d;
    const void* W   = isrc ? W_s : W_d;
    u16* out        = isrc ? ms : md;
    const int N     = isrc ? NS_N : ND_N;
    const int bid   = isrc ? blockIdx.x : blockIdx.x - half;
    const int nb    = isrc ? half : gridDim.x - half;

    for (int i = tid; i < C * C; i += blockDim.x) {
        int k = i >> 6, c = i & 63;
        sW[((k >> 1) << 7) + (c << 1) + (k & 1)] = loadb(W, i, isbf);
    }
    if (tid < C) {
        slnw[tid] = loadf(lnw, tid, isbf);
        slnb[tid] = loadf(lnb, tid, isbf);
        sbias[tid] = isrc ? 0.f : loadf(b_d, tid, isbf);
    }
    __syncthreads();

    const int wave = tid >> 6, lane = tid & 63;
    const u32* w = (const u32*)sW;
    const int gw = bid * 4 + wave, nw = nb * 4;
    for (int n = gw; n < N; n += nw) {
        float x = loadf(xf, (size_t)n * C + lane, isbf);
        float mean = waveAllSum(x) * (1.f / 64.f);
        float xc = x - mean;
        float var = waveAllSum(xc * xc) * (1.f / 64.f);
        float y = xc * rsqrtf(var + EPSV) * slnw[lane] + slnb[lane];
        WB();
        ybuf[wave][lane] = y;
        WB();
        float acc = sbias[lane];
        #pragma unroll 8
        for (int k2 = 0; k2 < 32; ++k2) {
            float2 yv = *(const float2*)&ybuf[wave][k2 * 2];
            u32 wp = w[(k2 << 6) + lane];
            acc += yv.x * lo16(wp) + yv.y * hi16(wp);
        }
        WB();
        out[(size_t)n * C + lane] = f2bbits(acc);
        WB();
    }
}

// ================= FAST PATH: MFMA edge kernel, perm-ordered, XOR-swizzled LDS ======
// Full depth-1 pipeline: next tile's es/ea/elg prefetched under GEMM1; current
// tile's bf16 ms/md gathers issued at body top (covered by GEMM1+ea phases).
// amdgpu_waves_per_eu(4,4): occupancy is LDS-capped at 4 waves/SIMD anyway; pin
// the allocator there so it uses the 128-VGPR budget instead of spilling (R2 bug).
__attribute__((amdgpu_waves_per_eu(4, 4)))
__launch_bounds__(512)
__global__ void edge_mfma_kernel(const void* __restrict__ edge_attr,
                                 const void* __restrict__ edge_scalars,
                                 const void* __restrict__ edge_logits,
                                 const int* __restrict__ edge_src,
                                 const int* __restrict__ edge_dst,
                                 const int* __restrict__ perm,
                                 const void* __restrict__ W_ea, const void* __restrict__ W_dtp,
                                 const void* __restrict__ W_r1, const void* __restrict__ b_r1,
                                 const void* __restrict__ W_r2, const void* __restrict__ b_r2,
                                 const void* __restrict__ alpha_vec,
                                 const int* __restrict__ flagp,
                                 const u16* __restrict__ ms, const u16* __restrict__ md,
                                 u16* __restrict__ valbuf, float* __restrict__ logitsbuf) {
    // XOR-swizzled rows: element group g (8 u16) of row n stored at group g^(n&7)
    __shared__ u16 sWr1T[C * SD];        // 8 KB  [n=64][k=64]
    __shared__ u16 sWr2T[2 * C * SD];    // 16 KB [n=128][k=64]
    __shared__ u16 sWdtpT[2 * C * C];    // 16 KB [n=128][k=64]
    __shared__ u16 sWeaT[C * 32];        // 4 KB  [n=64][k=32] linear (already conflict-min)
    __shared__ float sbr1[SD], sbr2[2 * C], salpha[C];
    __shared__ u16 scratch[8][2][16 * C];  // 32 KB, swizzled rows (per-wave)

    const int isbf = *flagp;
    const int tid = threadIdx.x;
    for (int i = tid; i < SD * SD; i += 512) {
        int k = i >> 6, n = i & 63;
        sWr1T[n * 64 + (((k >> 3) ^ (n & 7)) << 3) + (k & 7)] = loadb(W_r1, i, isbf);
    }
    for (int i = tid; i < SD * 2 * C; i += 512) {
        int k = i >> 7, n = i & 127;
        sWr2T[n * 64 + (((k >> 3) ^ (n & 7)) << 3) + (k & 7)] = loadb(W_r2, i, isbf);
    }
    for (int i = tid; i < C * 2 * C; i += 512) {
        int k = i >> 7, n = i & 127;
        sWdtpT[n * 64 + (((k >> 3) ^ (n & 7)) << 3) + (k & 7)] = loadb(W_dtp, i, isbf);
    }
    for (int i = tid; i < C * 32; i += 512) {
        int n = i >> 5, k = i & 31;
        sWeaT[i] = (k < AD) ? loadb(W_ea, (size_t)k * C + n, isbf) : (u16)0;
    }
    for (int i = tid; i < SD; i += 512) sbr1[i] = loadf(b_r1, i, isbf);
    for (int i = tid; i < 2 * C; i += 512) sbr2[i] = loadf(b_r2, i, isbf);
    for (int i = tid; i < C; i += 512) salpha[i] = loadf(alpha_vec, i, isbf);
    __syncthreads();

    const int wv = tid >> 6, lane = tid & 63;
    const int m15 = lane & 15, quad = lane >> 4;
    const int sw = m15 & 7;            // row&7 for rows indexed by m15 (weights n and tiles)
    const int pg0 = (quad ^ sw) << 3;  // physical byte-group offset for logical group quad
    const int pg1 = pg0 ^ 32;          // logical group quad+4
    u16* scr_r = scratch[wv][0];
    u16* scr_e = scratch[wv][1];

    const int NT = NE_E / 16;
    const int stride = gridDim.x * 8;
    int t = blockIdx.x * 8 + wv;

    // ---- prologue: first tile's indices + operands
    int e = 0, s = 0, dd = 0;
    short8 esA0 = 0, esA1 = 0, eaA = 0;
    float elg_lane = 0.f;
    if (t < NT) {
        e = perm[t * 16 + m15];
        s = edge_src[e];
        dd = edge_dst[e];
        esA0 = load8bf(edge_scalars, (size_t)e * SD + quad * 8, isbf);
        esA1 = load8bf(edge_scalars, (size_t)e * SD + 32 + quad * 8, isbf);
        elg_lane = loadf(edge_logits, e, isbf);
        if (quad < 2) eaA = load8bf(edge_attr, (size_t)e * AD + quad * 8, isbf);
    }

    while (t < NT) {
        const int tn = t + stride;
        const int e0 = t * 16;
        // ---- current tile's bf16 gathers (s/dd from rotation); GEMM1+ea cover latency
        const u16* msr = ms + (size_t)s * C;
        const u16* mdr = md + (size_t)dd * C;
        short8 gms0 = *(const short8*)&msr[quad * 8];
        short8 gms1 = *(const short8*)&msr[32 + quad * 8];
        short8 gmd0 = *(const short8*)&mdr[quad * 8];
        short8 gmd1 = *(const short8*)&mdr[32 + quad * 8];
        // ---- next tile's perm entry (consumed after GEMM1)
        int eN = 0;
        if (tn < NT) eN = perm[tn * 16 + m15];
        WB();
        // ---- GEMM1: r = silu(es @ W_r1 + b) -> scr_r (swizzled [m][k])
        #pragma unroll
        for (int nt = 0; nt < 4; ++nt) {
            f32x4 c = {0.f, 0.f, 0.f, 0.f};
            c = MFMA16(esA0, *(const short8*)&sWr1T[(nt * 16 + m15) * 64 + pg0], c);
            c = MFMA16(esA1, *(const short8*)&sWr1T[(nt * 16 + m15) * 64 + pg1], c);
            float bc = sbr1[nt * 16 + m15];
            int lg = nt * 2 + (m15 >> 3);
            int o = m15 & 7;
            #pragma unroll
            for (int r = 0; r < 4; ++r) {
                float f = c[r] + bc;
                f = f / (1.f + __expf(-f));
                int row = quad * 4 + r;
                scr_r[row * 64 + ((lg ^ (row & 7)) << 3) + o] = f2bbits(f);
            }
        }
        // ---- ea = edge_attr @ W_ea -> scr_e (swizzled)
        #pragma unroll
        for (int nt = 0; nt < 4; ++nt) {
            f32x4 c = {0.f, 0.f, 0.f, 0.f};
            c = MFMA16(eaA, *(const short8*)&sWeaT[(nt * 16 + m15) * 32 + quad * 8], c);
            int lg = nt * 2 + (m15 >> 3);
            int o = m15 & 7;
            #pragma unroll
            for (int r = 0; r < 4; ++r) {
                int row = quad * 4 + r;
                scr_e[row * 64 + ((lg ^ (row & 7)) << 3) + o] = f2bbits(c[r]);
            }
        }
        // ---- prefetch next tile's indices + operands (eN arrived under GEMM1)
        int sN = 0, ddN = 0;
        short8 esN0 = 0, esN1 = 0, eaN = 0;
        float elgN = 0.f;
        if (tn < NT) {
            sN = edge_src[eN];
            ddN = edge_dst[eN];
            esN0 = load8bf(edge_scalars, (size_t)eN * SD + quad * 8, isbf);
            esN1 = load8bf(edge_scalars, (size_t)eN * SD + 32 + quad * 8, isbf);
            elgN = loadf(edge_logits, eN, isbf);
            if (quad < 2) eaN = load8bf(edge_attr, (size_t)eN * AD + quad * 8, isbf);
        }
        WB();
        short8 rA0 = *(const short8*)&scr_r[m15 * 64 + pg0];
        short8 rA1 = *(const short8*)&scr_r[m15 * 64 + pg1];
        short8 ev0 = *(const short8*)&scr_e[m15 * 64 + pg0];
        short8 ev1 = *(const short8*)&scr_e[m15 * 64 + pg1];
        short8 xA0, xA1;
        #pragma unroll
        for (int j = 0; j < 8; ++j) {
            float a = b2fu((u16)gms0[j]) + b2fu((u16)gmd0[j]);
            xA0[j] = (short)f2bbits(a * b2fu((u16)ev0[j]));
            float b = b2fu((u16)gms1[j]) + b2fu((u16)gmd1[j]);
            xA1[j] = (short)f2bbits(b * b2fu((u16)ev1[j]));
        }
        float elg_q[4];
        #pragma unroll
        for (int r = 0; r < 4; ++r) elg_q[r] = __shfl(elg_lane, quad * 4 + r, 64);
        WB();
        // ---- dual GEMM: w_edge & dtp over 8 N-tiles
        #pragma unroll
        for (int nt = 0; nt < 8; ++nt) {
            f32x4 w = {0.f, 0.f, 0.f, 0.f};
            w = MFMA16(rA0, *(const short8*)&sWr2T[(nt * 16 + m15) * 64 + pg0], w);
            w = MFMA16(rA1, *(const short8*)&sWr2T[(nt * 16 + m15) * 64 + pg1], w);
            f32x4 dv = {0.f, 0.f, 0.f, 0.f};
            dv = MFMA16(xA0, *(const short8*)&sWdtpT[(nt * 16 + m15) * 64 + pg0], dv);
            dv = MFMA16(xA1, *(const short8*)&sWdtpT[(nt * 16 + m15) * 64 + pg1], dv);
            float wb = sbr2[nt * 16 + m15];
            if (nt < 4) {
                float sa = salpha[nt * 16 + m15];
                #pragma unroll
                for (int r = 0; r < 4; ++r) {
                    float v = dv[r] * (w[r] + wb);
                    float lf = (v >= 0.f) ? v : 0.2f * v;
                    float tt = lf * sa;
                    tt += __shfl_xor(tt, 1, 64);
                    tt += __shfl_xor(tt, 2, 64);
                    tt += __shfl_xor(tt, 4, 64);
                    if ((lane & 7) == 0)
                        logitsbuf[(size_t)(e0 + quad * 4 + r) * NH + nt * 2 + ((lane >> 3) & 1)]
                            = tt + elg_q[r];
                }
            } else {
                int lg = (nt - 4) * 2 + (m15 >> 3);
                int o = m15 & 7;
                #pragma unroll
                for (int r = 0; r < 4; ++r) {
                    float v = dv[r] * (w[r] + wb);
                    int row = quad * 4 + r;
                    scr_r[row * 64 + ((lg ^ (row & 7)) << 3) + o] = f2bbits(v);
                }
            }
        }
        WB();
        // ---- coalesced val store (slot-ordered rows)
        {
            int row = lane >> 2, seg = lane & 3;
            int rw7 = row & 7;
            uint4 v0 = *(const uint4*)&scr_r[row * 64 + (((seg * 2) ^ rw7) << 3)];
            uint4 v1 = *(const uint4*)&scr_r[row * 64 + (((seg * 2 + 1) ^ rw7) << 3)];
            uint4* gp = (uint4*)&valbuf[(size_t)(e0 + row) * C + seg * 16];
            gp[0] = v0; gp[1] = v1;
        }
        WB();
        // ---- rotate pipeline registers
        t = tn;
        e = eN; s = sN; dd = ddN;
        esA0 = esN0; esA1 = esN1; eaA = eaN; elg_lane = elgN;
    }
}

// ================= aggregate: contiguous slots, 2-way unrolled online softmax =======
__global__ void aggregate_kernel(const int* __restrict__ row_ptr,
                                 const float* __restrict__ logitsbuf,
                                 const u16* __restrict__ valbuf,
                                 float* __restrict__ attout) {
    const int wave = threadIdx.x >> 6, lane = threadIdx.x & 63;
    const int head = lane >> 3;
    const int gw = blockIdx.x * 4 + wave, nw = gridDim.x * 4;
    for (int d = gw; d < ND_N; d += nw) {
        const int beg = row_ptr[d], end = row_ptr[d + 1];
        float m0 = -__builtin_inff(), z0 = 0.f, a0 = 0.f;
        float m1 = -__builtin_inff(), z1 = 0.f, a1 = 0.f;
        int i = beg;
        for (; i + 1 < end; i += 2) {
            float lg0 = logitsbuf[(size_t)i * NH + head];
            float lg1 = logitsbuf[(size_t)(i + 1) * NH + head];
            float v0 = b2fu(valbuf[(size_t)i * C + lane]);
            float v1 = b2fu(valbuf[(size_t)(i + 1) * C + lane]);
            float mn0 = fmaxf(m0, lg0);
            float mn1 = fmaxf(m1, lg1);
            float sc0 = __expf(m0 - mn0);
            float sc1 = __expf(m1 - mn1);
            float e0 = __expf(lg0 - mn0);
            float e1 = __expf(lg1 - mn1);
            z0 = z0 * sc0 + e0; a0 = a0 * sc0 + e0 * v0; m0 = mn0;
            z1 = z1 * sc1 + e1; a1 = a1 * sc1 + e1 * v1; m1 = mn1;
        }
        if (i < end) {
            float lg0 = logitsbuf[(size_t)i * NH + head];
            float v0 = b2fu(valbuf[(size_t)i * C + lane]);
            float mn = fmaxf(m0, lg0);
            float sc = __expf(m0 - mn);
            float e0 = __expf(lg0 - mn);
            z0 = z0 * sc + e0; a0 = a0 * sc + e0 * v0; m0 = mn;
        }
        // merge the two chains (empty-chain safe)
        float mn = fmaxf(m0, m1);
        float s0 = __expf(m0 - mn);
        float s1 = __expf(m1 - mn);
        float z = z0 * s0 + z1 * s1;
        float acc = a0 * s0 + a1 * s1;
        attout[(size_t)d * C + lane] = (z > 0.f) ? acc / z : 0.f;
    }
}

// ================= SLOW PATH edge kernel (fallback; bf16 ms/md) =====================
__global__ void edge_csr_kernel(const void* __restrict__ edge_attr,
                                const void* __restrict__ edge_scalars,
                                const void* __restrict__ edge_logits,
                                const int* __restrict__ edge_src,
                                const int* __restrict__ row_ptr, const int* __restrict__ perm,
                                const void* __restrict__ W_ea, const void* __restrict__ W_dtp,
                                const void* __restrict__ W_r1, const void* __restrict__ b_r1,
                                const void* __restrict__ W_r2, const void* __restrict__ b_r2,
                                const void* __restrict__ alpha_vec,
                                const int* __restrict__ flagp,
                                const u16* __restrict__ ms, const u16* __restrict__ md,
                                float* __restrict__ attout) {
    __shared__ u16 sWr1[SD * SD];
    __shared__ u16 sWr2[SD * 2 * C];
    __shared__ u16 sWdtp[C * 2 * C];
    __shared__ u16 sWea[AD * C];
    __shared__ float sbr1[SD], sbr2[2 * C], salpha[C];
    __shared__ float sbuf[4][2][C];

    const int isbf = *flagp;
    const int tid = threadIdx.x;
    {
        for (int i = tid; i < SD * SD; i += blockDim.x) {
            int k = i >> 6, c = i & 63;
            sWr1[((k >> 1) << 7) + (c << 1) + (k & 1)] = loadb(W_r1, i, isbf);
        }
        for (int i = tid; i < SD * 2 * C; i += blockDim.x) {
            int k = i >> 7, c = i & 127;
            sWr2[(k << 7) + ((c & 63) << 1) + (c >> 6)] = loadb(W_r2, i, isbf);
        }
        for (int i = tid; i < C * 2 * C; i += blockDim.x) {
            int k = i >> 7, c = i & 127;
            sWdtp[(k << 7) + ((c & 63) << 1) + (c >> 6)] = loadb(W_dtp, i, isbf);
        }
        for (int i = tid; i < AD * C; i += blockDim.x) {
            int k = i >> 6, c = i & 63;
            sWea[((k >> 1) << 7) + (c << 1) + (k & 1)] = loadb(W_ea, i, isbf);
        }
        for (int i = tid; i < SD; i += blockDim.x) sbr1[i] = loadf(b_r1, i, isbf);
        for (int i = tid; i < 2 * C; i += blockDim.x) sbr2[i] = loadf(b_r2, i, isbf);
        for (int i = tid; i < C; i += blockDim.x) salpha[i] = loadf(alpha_vec, i, isbf);
    }
    __syncthreads();

    const int wave = tid >> 6, lane = tid & 63;
    float* buf0 = sbuf[wave][0];
    float* buf1 = sbuf[wave][1];
    const u32* wr1 = (const u32*)sWr1;
    const u32* wr2 = (const u32*)sWr2;
    const u32* wdtp = (const u32*)sWdtp;
    const u32* wea = (const u32*)sWea;
    const int gw = blockIdx.x * 4 + wave, nw = gridDim.x * 4;

    for (int d = gw; d < ND_N; d += nw) {
        const int beg = row_ptr[d], end = row_ptr[d + 1];
        const float mdv = b2fu(md[(size_t)d * C + lane]);
        float m = -__builtin_inff(), z = 0.f, acc = 0.f;

        for (int i = beg; i < end; ++i) {
            const int e = perm[i];
            WB();
            buf0[lane] = loadf(edge_scalars, (size_t)e * SD + lane, isbf);
            WB();
            float accr = sbr1[lane];
            #pragma unroll 8
            for (int k2 = 0; k2 < 32; ++k2) {
                float2 xv = *(const float2*)&buf0[k2 * 2];
                u32 wp = wr1[(k2 << 6) + lane];
                accr += xv.x * lo16(wp) + xv.y * hi16(wp);
            }
            float r = accr / (1.f + __expf(-accr));
            WB();
            buf1[lane] = r;
            WB();
            float we0 = sbr2[lane], we1 = sbr2[lane + C];
            #pragma unroll 8
            for (int k = 0; k < SD; ++k) {
                float rk = buf1[k];
                u32 wp = wr2[(k << 6) + lane];
                we0 += rk * lo16(wp);
                we1 += rk * hi16(wp);
            }
            WB();
            if (lane < AD) buf0[lane] = loadf(edge_attr, (size_t)e * AD + lane, isbf);
            WB();
            float eav = 0.f;
            #pragma unroll
            for (int k2 = 0; k2 < 8; ++k2) {
                float2 xv = *(const float2*)&buf0[k2 * 2];
                u32 wp = wea[(k2 << 6) + lane];
                eav += xv.x * lo16(wp) + xv.y * hi16(wp);
            }
            const int s = edge_src[e];
            float x = (b2fu(ms[(size_t)s * C + lane]) + mdv) * eav;
            WB();
            buf1[lane] = x;
            WB();
            float dt0 = 0.f, dt1 = 0.f;
            #pragma unroll 8
            for (int k = 0; k < C; ++k) {
                float xk = buf1[k];
                u32 wp = wdtp[(k << 6) + lane];
                dt0 += xk * lo16(wp);
                dt1 += xk * hi16(wp);
            }
            dt0 *= we0;
            dt1 *= we1;
            float lf = (dt0 >= 0.f) ? dt0 : 0.2f * dt0;
            float t = lf * salpha[lane];
            t += __shfl_xor(t, 1, 64);
            t += __shfl_xor(t, 2, 64);
            t += __shfl_xor(t, 4, 64);
            float lg = t + loadf(edge_logits, e, isbf);
            float mn = fmaxf(m, lg);
            float sc = __expf(m - mn);
            float a = __expf(lg - mn);
            z = z * sc + a;
            acc = acc * sc + a * dt1;
            m = mn;
        }
        attout[(size_t)d * C + lane] = (z > 0.f) ? acc / z : 0.f;
    }
}

// ================= FAST PATH final: MFMA epilogue (16 nodes / wave-tile) ============
// 8-wave blocks: weights shared by 8 waves, 1 block/CU but 8 waves/CU.
__launch_bounds__(512, 2)
__global__ void final_mfma_kernel(const void* __restrict__ dst_f,
                                  const float* __restrict__ attout,
                                  const void* __restrict__ W_proj, const void* __restrict__ b_proj,
                                  const void* __restrict__ ln_w, const void* __restrict__ ln_b,
                                  const void* __restrict__ W_f1, const void* __restrict__ b_f1,
                                  const void* __restrict__ W_f2, const void* __restrict__ b_f2,
                                  const int* __restrict__ flagp,
                                  void* __restrict__ out) {
    // XOR-swizzled weight rows (group g of row n at g^(n&7))
    __shared__ u16 sWpT[C * C];         // 8 KB   [n=64][k=64]
    __shared__ u16 sWf1T[MF * C];       // 24 KB  [n=192][k=64]
    __shared__ u16 sWf2T[C * MF];       // 24 KB  [n=64][k=192]
    __shared__ float sbp[C], slnw[C], slnb[C], sbf1[MF], sbf2[C];
    __shared__ uint4 scr4[8][400];      // 6400 B per wave, phase-aliased scratch

    const int isbf = *flagp;
    const int tid = threadIdx.x;       // blockDim = 512 (8 waves)
    for (int i = tid; i < C * C; i += 512) {
        int k = i >> 6, n = i & 63;
        sWpT[n * 64 + (((k >> 3) ^ (n & 7)) << 3) + (k & 7)] = loadb(W_proj, i, isbf);
    }
    for (int i = tid; i < C * MF; i += 512) {
        int k = i / MF, n = i - k * MF;     // W_f1[k][n], n<192
        sWf1T[n * 64 + (((k >> 3) ^ (n & 7)) << 3) + (k & 7)] = loadb(W_f1, i, isbf);
    }
    for (int i = tid; i < MF * C; i += 512) {
        int k = i >> 6, n = i & 63;         // W_f2[k][n], k<192
        sWf2T[n * 192 + (((k >> 3) ^ (n & 7)) << 3) + (k & 7)] = loadb(W_f2, i, isbf);
    }
    for (int i = tid; i < C; i += 512) {
        sbp[i] = loadf(b_proj, i, isbf);
        slnw[i] = loadf(ln_w, i, isbf);
        slnb[i] = loadf(ln_b, i, isbf);
        sbf2[i] = loadf(b_f2, i, isbf);
    }
    for (int i = tid; i < MF; i += 512) sbf1[i] = loadf(b_f1, i, isbf);
    __syncthreads();

    const int wv = tid >> 6, lane = tid & 63;
    const int m15 = lane & 15, quad = lane >> 4;
    const int sw = m15 & 7;
    const int pg0 = (quad ^ sw) << 3;
    const int pg1 = pg0 ^ 32;
    u16* scr = (u16*)scr4[wv];
    float* scrf = (float*)scr4[wv];

    for (int t = blockIdx.x * 8 + wv; t < ND_N / 16; t += gridDim.x * 8) {
        const int n0 = t * 16;
        short8 oA0 = load8bf(attout, (size_t)(n0 + m15) * C + quad * 8, 0);
        short8 oA1 = load8bf(attout, (size_t)(n0 + m15) * C + 32 + quad * 8, 0);
        float emb[4][4];
        #pragma unroll
        for (int nt = 0; nt < 4; ++nt) {
            f32x4 c = {0.f, 0.f, 0.f, 0.f};
            c = MFMA16(oA0, *(const short8*)&sWpT[(nt * 16 + m15) * 64 + pg0], c);
            c = MFMA16(oA1, *(const short8*)&sWpT[(nt * 16 + m15) * 64 + pg1], c);
            int col = nt * 16 + m15;
            float bp = sbp[col];
            #pragma unroll
            for (int r = 0; r < 4; ++r)
                emb[nt][r] = c[r] + bp + loadf(dst_f, (size_t)(n0 + quad * 4 + r) * C + col, isbf);
        }
        float y[4][4];
        #pragma unroll
        for (int r = 0; r < 4; ++r) {
            float part = emb[0][r] + emb[1][r] + emb[2][r] + emb[3][r];
            part += __shfl_xor(part, 1, 64);
            part += __shfl_xor(part, 2, 64);
            part += __shfl_xor(part, 4, 64);
            part += __shfl_xor(part, 8, 64);
            float mean = part * (1.f / 64.f);
            float q = 0.f;
            #pragma unroll
            for (int nt = 0; nt < 4; ++nt) {
                float d = emb[nt][r] - mean;
                q += d * d;
            }
            q += __shfl_xor(q, 1, 64);
            q += __shfl_xor(q, 2, 64);
            q += __shfl_xor(q, 4, 64);
            q += __shfl_xor(q, 8, 64);
            float rs = rsqrtf(q * (1.f / 64.f) + EPSV);
            #pragma unroll
            for (int nt = 0; nt < 4; ++nt) {
                int col = nt * 16 + m15;
                y[nt][r] = (emb[nt][r] - mean) * rs * slnw[col] + slnb[col];
            }
        }
        WB();
        #pragma unroll
        for (int nt = 0; nt < 4; ++nt)
            #pragma unroll
            for (int r = 0; r < 4; ++r)
                scr[(quad * 4 + r) * 72 + nt * 16 + m15] = f2bbits(y[nt][r]);
        WB();
        short8 yA0 = *(const short8*)&scr[m15 * 72 + quad * 8];
        short8 yA1 = *(const short8*)&scr[m15 * 72 + 32 + quad * 8];
        WB();
        #pragma unroll
        for (int nt = 0; nt < 12; ++nt) {
            f32x4 g = {0.f, 0.f, 0.f, 0.f};
            g = MFMA16(yA0, *(const short8*)&sWf1T[(nt * 16 + m15) * 64 + pg0], g);
            g = MFMA16(yA1, *(const short8*)&sWf1T[(nt * 16 + m15) * 64 + pg1], g);
            int col = nt * 16 + m15;
            float bg = sbf1[col];
            #pragma unroll
            for (int r = 0; r < 4; ++r) {
                float f = g[r] + bg;
                f = f / (1.f + __expf(-f));
                scr[(quad * 4 + r) * 200 + col] = f2bbits(f);
            }
        }
        WB();
        short8 gA[6];
        #pragma unroll
        for (int j = 0; j < 6; ++j)
            gA[j] = *(const short8*)&scr[m15 * 200 + j * 32 + quad * 8];
        WB();
        #pragma unroll
        for (int nt = 0; nt < 4; ++nt) {
            f32x4 c = {0.f, 0.f, 0.f, 0.f};
            #pragma unroll
            for (int j = 0; j < 6; ++j) {
                int lg = j * 4 + quad;           // logical group in 24-group row
                int pg = (lg ^ sw) << 3;         // n&7 = m15&7 = sw
                c = MFMA16(gA[j], *(const short8*)&sWf2T[(nt * 16 + m15) * 192 + pg], c);
            }
            int col = nt * 16 + m15;
            float bf = sbf2[col];
            #pragma unroll
            for (int r = 0; r < 4; ++r)
                scrf[(quad * 4 + r) * 68 + col] = c[r] + bf + emb[nt][r];
        }
        WB();
        {
            int row = lane >> 2, seg = lane & 3;
            if (isbf) {
                u16* gp = (u16*)out + (size_t)(n0 + row) * C + seg * 16;
                #pragma unroll
                for (int j = 0; j < 4; ++j) {
                    float4 v = *(const float4*)&scrf[row * 68 + seg * 16 + j * 4];
                    u32 p0 = (u32)f2bbits(v.x) | ((u32)f2bbits(v.y) << 16);
                    u32 p1 = (u32)f2bbits(v.z) | ((u32)f2bbits(v.w) << 16);
                    uint2 pk = {p0, p1};
                    *(uint2*)(gp + j * 4) = pk;
                }
            } else {
                float* gp = (float*)out + (size_t)(n0 + row) * C + seg * 16;
                #pragma unroll
                for (int j = 0; j < 4; ++j)
                    *(float4*)(gp + j * 4) = *(const float4*)&scrf[row * 68 + seg * 16 + j * 4];
            }
        }
        WB();
    }
}

// ================= SLOW PATH final (scalar) ========================================
__global__ void final_scalar_kernel(const void* __restrict__ dst_f,
                                    const float* __restrict__ attout,
                                    const void* __restrict__ W_proj, const void* __restrict__ b_proj,
                                    const void* __restrict__ ln_w, const void* __restrict__ ln_b,
                                    const void* __restrict__ W_f1, const void* __restrict__ b_f1,
                                    const void* __restrict__ W_f2, const void* __restrict__ b_f2,
                                    const int* __restrict__ flagp,
                                    void* __restrict__ out) {
    __shared__ u16 sWp[C * C];
    __shared__ u16 sWf1p[C * 2 * C];
    __shared__ u16 sWf1c[C * C];
    __shared__ u16 sWf2[MF * C];
    __shared__ float sbp[C], slnw[C], slnb[C], sbf1[MF], sbf2[C];
    __shared__ float ybuf[4][C];
    __shared__ float gbuf[4][MF];

    const int isbf = *flagp;
    const int tid = threadIdx.x;
    {
        for (int i = tid; i < C * C; i += blockDim.x) {
            int k = i >> 6, c = i & 63;
            sWp[((k >> 1) << 7) + (c << 1) + (k & 1)] = loadb(W_proj, i, isbf);
        }
        for (int i = tid; i < C * MF; i += blockDim.x) {
            int k = i / MF, c = i - k * MF;
            u16 b = loadb(W_f1, i, isbf);
            if (c < 128) sWf1p[(k << 7) + ((c & 63) << 1) + (c >> 6)] = b;
            else         sWf1c[(k << 6) + (c - 128)] = b;
        }
        for (int i = tid; i < MF * C; i += blockDim.x) {
            int k = i >> 6, c = i & 63;
            sWf2[((k >> 1) << 7) + (c << 1) + (k & 1)] = loadb(W_f2, i, isbf);
        }
        for (int i = tid; i < C; i += blockDim.x) {
            sbp[i] = loadf(b_proj, i, isbf);
            slnw[i] = loadf(ln_w, i, isbf);
            slnb[i] = loadf(ln_b, i, isbf);
            sbf2[i] = loadf(b_f2, i, isbf);
        }
        for (int i = tid; i < MF; i += blockDim.x) sbf1[i] = loadf(b_f1, i, isbf);
    }
    __syncthreads();

    const int wave = tid >> 6, lane = tid & 63;
    const u32* wp32 = (const u32*)sWp;
    const u32* wf1 = (const u32*)sWf1p;
    const u32* wf2 = (const u32*)sWf2;
    const int gw = blockIdx.x * 4 + wave, nw = gridDim.x * 4;

    for (int n = gw; n < ND_N; n += nw) {
        float o = attout[(size_t)n * C + lane];
        WB();
        ybuf[wave][lane] = o;
        WB();
        float p = sbp[lane];
        #pragma unroll 8
        for (int k2 = 0; k2 < 32; ++k2) {
            float2 yv = *(const float2*)&ybuf[wave][k2 * 2];
            u32 wv = wp32[(k2 << 6) + lane];
            p += yv.x * lo16(wv) + yv.y * hi16(wv);
        }
        float emb = p + loadf(dst_f, (size_t)n * C + lane, isbf);
        float mean = waveAllSum(emb) * (1.f / 64.f);
        float ec = emb - mean;
        float var = waveAllSum(ec * ec) * (1.f / 64.f);
        float y = ec * rsqrtf(var + EPSV) * slnw[lane] + slnb[lane];
        WB();
        ybuf[wave][lane] = y;
        WB();
        float g0 = sbf1[lane], g1v = sbf1[lane + C], g2v = sbf1[lane + 2 * C];
        #pragma unroll 8
        for (int k = 0; k < C; ++k) {
            float yk = ybuf[wave][k];
            u32 wv = wf1[(k << 6) + lane];
            union { u32 u; float f; } cv; cv.u = ((u32)sWf1c[(k << 6) + lane]) << 16;
            g0 += yk * lo16(wv);
            g1v += yk * hi16(wv);
            g2v += yk * cv.f;
        }
        WB();
        gbuf[wave][lane] = g0 / (1.f + __expf(-g0));
        gbuf[wave][lane + C] = g1v / (1.f + __expf(-g1v));
        gbuf[wave][lane + 2 * C] = g2v / (1.f + __expf(-g2v));
        WB();
        float f = sbf2[lane];
        #pragma unroll 8
        for (int k2 = 0; k2 < 96; ++k2) {
            float2 gv = *(const float2*)&gbuf[wave][k2 * 2];
            u32 wv = wf2[(k2 << 6) + lane];
            f += gv.x * lo16(wv) + gv.y * hi16(wv);
        }
        WB();
        float res = f + emb;
        if (isbf) ((bf16*)out)[(size_t)n * C + lane] = __float2bfloat16(res);
        else      ((float*)out)[(size_t)n * C + lane] = res;
    }
}

extern "C" void kernel_launch(void* const* d_in, const int* in_sizes, int n_in,
                              void* d_out, int out_size, void* d_ws, size_t ws_size,
                              hipStream_t stream) {
    const void* src_f        = d_in[0];
    const void* dst_f        = d_in[1];
    const void* edge_attr    = d_in[2];
    const void* edge_scalars = d_in[3];
    const void* edge_logits  = d_in[4];
    const int*  edge_src     = (const int*)d_in[5];
    const int*  edge_dst     = (const int*)d_in[6];
    const void* ln_src_w = d_in[7];
    const void* ln_src_b = d_in[8];
    const void* W_src    = d_in[9];
    const void* ln_dst_w = d_in[10];
    const void* ln_dst_b = d_in[11];
    const void* W_dst    = d_in[12];
    const void* b_dst    = d_in[13];
    const void* W_ea     = d_in[14];
    const void* W_dtp    = d_in[15];
    const void* W_r1     = d_in[16];
    const void* b_r1     = d_in[17];
    const void* W_r2     = d_in[18];
    const void* b_r2     = d_in[19];
    const void* alpha_vec = d_in[20];
    const void* W_proj   = d_in[21];
    const void* b_proj   = d_in[22];
    const void* ln_post_w = d_in[23];
    const void* ln_post_b = d_in[24];
    const void* W_f1     = d_in[25];
    const void* b_f1     = d_in[26];
    const void* W_f2     = d_in[27];
    const void* b_f2     = d_in[28];

    // ---- workspace layout (ms/md regions sized for fp32 but hold bf16 content;
    //      ms region reused as fp32 attout after the edge kernel) ----
    int* flag     = (int*)d_ws;                         // 16 ints
    float* msf    = (float*)d_ws + 16;                  // NS*C fp32-sized region
    float* mdf    = msf + (size_t)NS_N * C;             // ND*C fp32-sized region
    u16* ms16     = (u16*)msf;
    u16* md16     = (u16*)mdf;
    int* cnt      = (int*)(mdf + (size_t)ND_N * C);     // ND
    int* row_ptr  = cnt + ND_N;                         // ND+1 (padded)
    int* cursor   = row_ptr + (ND_N + 4);               // ND
    int* perm     = cursor + ND_N;                      // E
    float* logitsbuf = (float*)(perm + NE_E);           // fast: E*NH (slot-indexed)
    u16* valbuf      = (u16*)(logitsbuf + (size_t)NE_E * NH); // fast: E*C bf16 (slot-indexed)
    float* attout_slow = (float*)(perm + NE_E);         // slow: ND*C (aliases logitsbuf)

    size_t base_b = (size_t)(16 + NS_N * C + ND_N * C) * 4
                  + ((size_t)ND_N * 3 + 4 + NE_E) * 4;
    size_t need_fast = base_b + (size_t)NE_E * NH * 4 + (size_t)NE_E * C * 2;
    size_t need_slow = base_b + (size_t)ND_N * C * 4;
    int fast = (ws_size >= need_fast) ? 1 : 0;
    if (!fast && ws_size < need_slow) return;

    // detect + cnt-zero fused
    detect_zero_kernel<<<1 + (ND_N + 255) / 256, 256, 0, stream>>>(src_f, flag, cnt);
    hist_kernel<<<(NE_E + 255) / 256, 256, 0, stream>>>(edge_dst, cnt);
    scan_phase1<<<SCAN_NCH, 256, 0, stream>>>(cnt, perm);
    scan_phase3<<<SCAN_NCH, 256, 0, stream>>>(cnt, perm, row_ptr, cursor, &row_ptr[ND_N]);
    scatter_kernel<<<(NE_E + 255) / 256, 256, 0, stream>>>(edge_dst, cursor, perm);

    // fused dual node projection (bf16 outputs)
    node_proj2_kernel<<<2048, 256, 0, stream>>>(src_f, dst_f,
                                                ln_src_w, ln_src_b, W_src,
                                                ln_dst_w, ln_dst_b, W_dst, b_dst,
                                                flag, ms16, md16);

    if (fast) {
        edge_mfma_kernel<<<1024, 512, 0, stream>>>(edge_attr, edge_scalars, edge_logits,
                                                   edge_src, edge_dst, perm,
                                                   W_ea, W_dtp, W_r1, b_r1, W_r2, b_r2,
                                                   alpha_vec, flag, ms16, md16,
                                                   valbuf, logitsbuf);
        // ms region dead after edge kernel -> reuse as fp32 attout
        aggregate_kernel<<<2048, 256, 0, stream>>>(row_ptr, logitsbuf, valbuf, msf);
        final_mfma_kernel<<<256, 512, 0, stream>>>(dst_f, msf,
                                                   W_proj, b_proj, ln_post_w, ln_post_b,
                                                   W_f1, b_f1, W_f2, b_f2,
                                                   flag, d_out);
    } else {
        edge_csr_kernel<<<2048, 256, 0, stream>>>(edge_attr, edge_scalars, edge_logits,
                                                  edge_src, row_ptr, perm,
                                                  W_ea, W_dtp, W_r1, b_r1, W_r2, b_r2,
                                                  alpha_vec, flag, ms16, md16, attout_slow);
        final_scalar_kernel<<<1024, 256, 0, stream>>>(dst_f, attout_slow,
                                                      W_proj, b_proj, ln_post_w, ln_post_b,
                                                      W_f1, b_f1, W_f2, b_f2,
                                                      flag, d_out);
    }
}

// Round 6
// 603.840 us; speedup vs baseline: 1.0687x; 1.0687x over previous
//
#include <hip/hip_runtime.h>
#include <hip/hip_bf16.h>

typedef __hip_bfloat16 bf16;
typedef unsigned short u16;
typedef unsigned int u32;

#define NS_N 50000
#define ND_N 50000
#define NE_E 600000
#define C 64
#define AD 16
#define SD 64
#define NH 8
#define MF 192
#define EPSV 1e-5f

#define WB() __builtin_amdgcn_wave_barrier()

typedef short short8 __attribute__((ext_vector_type(8)));
typedef float f32x4 __attribute__((ext_vector_type(4)));
#define MFMA16(a, b, c) __builtin_amdgcn_mfma_f32_16x16x32_bf16(a, b, c, 0, 0, 0)

__device__ __forceinline__ float lo16(u32 u) {
    union { u32 i; float f; } v; v.i = u << 16; return v.f;
}
__device__ __forceinline__ float hi16(u32 u) {
    union { u32 i; float f; } v; v.i = u & 0xffff0000u; return v.f;
}
__device__ __forceinline__ float b2fu(u16 u) {
    union { u32 i; float f; } v; v.i = ((u32)u) << 16; return v.f;
}
__device__ __forceinline__ u16 f2bbits(float f) {   // RNE fp32->bf16 bits
    u32 u = __float_as_uint(f);
    u32 r = u + 0x7FFFu + ((u >> 16) & 1u);
    return (u16)(r >> 16);
}
// dtype-adaptive loads: isbf==1 -> buffer is bf16, else fp32
__device__ __forceinline__ float loadf(const void* p, size_t i, int isbf) {
    if (isbf) { union { u32 u; float f; } v; v.u = ((u32)((const u16*)p)[i]) << 16; return v.f; }
    return ((const float*)p)[i];
}
__device__ __forceinline__ u16 loadb(const void* p, size_t i, int isbf) {
    if (isbf) return ((const u16*)p)[i];
    return f2bbits(((const float*)p)[i]);
}
__device__ __forceinline__ short8 load8bf(const void* p, size_t off, int isbf) {
    if (isbf) return *(const short8*)((const u16*)p + off);
    const float4* q = (const float4*)((const float*)p + off);
    float4 f0 = q[0], f1 = q[1];
    short8 r;
    r[0] = (short)f2bbits(f0.x); r[1] = (short)f2bbits(f0.y);
    r[2] = (short)f2bbits(f0.z); r[3] = (short)f2bbits(f0.w);
    r[4] = (short)f2bbits(f1.x); r[5] = (short)f2bbits(f1.y);
    r[6] = (short)f2bbits(f1.z); r[7] = (short)f2bbits(f1.w);
    return r;
}

__device__ __forceinline__ float waveAllSum(float v) {
    #pragma unroll
    for (int off = 32; off >= 1; off >>= 1) v += __shfl_xor(v, off, 64);
    return v;
}

// ================= dtype detection + cnt zero (fused) =================
__global__ void detect_zero_kernel(const void* src, int* flag, int* cnt) {
    if (blockIdx.x == 0) {
        if (threadIdx.x < 64) {
            const u16* p = (const u16*)src;
            const int lane = threadIdx.x;
            int c = 0;
            #pragma unroll
            for (int j = 0; j < 32; ++j) {
                u16 w = p[(size_t)(lane * 32 + j) * 2];
                int e = (w >> 7) & 0xFF;
                if (w == 0 || (e >= 100 && e <= 150)) c++;
            }
            #pragma unroll
            for (int off = 32; off >= 1; off >>= 1) c += __shfl_xor(c, off, 64);
            if (lane == 0) *flag = (c > 1536) ? 1 : 0;
        }
    } else {
        int i = (blockIdx.x - 1) * blockDim.x + threadIdx.x;
        if (i < ND_N) cnt[i] = 0;
    }
}

// ================= CSR build =================
__global__ void hist_kernel(const int* __restrict__ edge_dst, int* __restrict__ cnt) {
    int e = blockIdx.x * blockDim.x + threadIdx.x;
    if (e < NE_E) atomicAdd(&cnt[edge_dst[e]], 1);
}

// ---- 2-phase parallel scan (chunk sums -> per-chunk scan w/ inline chunk-prefix) ----
#define SCAN_CHUNK 1024
#define SCAN_NCH ((ND_N + SCAN_CHUNK - 1) / SCAN_CHUNK)   // 49 (must be <= 64)

__global__ void scan_phase1(const int* __restrict__ cnt, int* __restrict__ chunksum) {
    __shared__ int wsum[4];
    const int b = blockIdx.x, tidx = threadIdx.x;    // 256 threads
    const int base = b * SCAN_CHUNK + tidx * 4;
    int s = 0;
    if (base + 3 < ND_N) {
        int4 v = *(const int4*)&cnt[base];
        s = v.x + v.y + v.z + v.w;
    } else {
        #pragma unroll
        for (int j = 0; j < 4; ++j) { int i = base + j; if (i < ND_N) s += cnt[i]; }
    }
    #pragma unroll
    for (int off = 32; off >= 1; off >>= 1) s += __shfl_xor(s, off, 64);
    const int wv = tidx >> 6, lane = tidx & 63;
    if (lane == 0) wsum[wv] = s;
    __syncthreads();
    if (tidx == 0) chunksum[b] = wsum[0] + wsum[1] + wsum[2] + wsum[3];
}

// phase3 with inlined chunk-offset scan (first wave recomputes the 49-entry prefix)
__global__ void scan_phase3(const int* __restrict__ cnt, const int* __restrict__ chunksum,
                            int* __restrict__ row_ptr, int* __restrict__ cursor,
                            int* __restrict__ row_ptr_last) {
    __shared__ int woff[4];
    __shared__ int choff_s;
    const int b = blockIdx.x, tidx = threadIdx.x;    // 256 threads
    if (tidx < 64) {
        int v = (tidx < SCAN_NCH) ? chunksum[tidx] : 0;
        int incl = v;
        #pragma unroll
        for (int off = 1; off < 64; off <<= 1) {
            int t = __shfl_up(incl, off, 64);
            if (tidx >= off) incl += t;
        }
        if (tidx == b) choff_s = incl - v;           // exclusive prefix for this chunk
        if (b == 0 && tidx == 63) *row_ptr_last = incl;  // grand total
    }
    const int base = b * SCAN_CHUNK + tidx * 4;
    int v[4];
    #pragma unroll
    for (int j = 0; j < 4; ++j) { int i = base + j; v[j] = (i < ND_N) ? cnt[i] : 0; }
    int s = v[0] + v[1] + v[2] + v[3];
    int incl = s;
    const int lane = tidx & 63, wv = tidx >> 6;
    #pragma unroll
    for (int off = 1; off < 64; off <<= 1) {
        int t = __shfl_up(incl, off, 64);
        if (lane >= off) incl += t;
    }
    if (lane == 63) woff[wv] = incl;
    __syncthreads();
    int cross = 0;
    for (int w = 0; w < wv; ++w) cross += woff[w];
    int run = choff_s + cross + (incl - s);
    #pragma unroll
    for (int j = 0; j < 4; ++j) {
        int i = base + j;
        if (i < ND_N) { row_ptr[i] = run; cursor[i] = run; }
        run += v[j];
    }
}

__global__ void scatter_kernel(const int* __restrict__ edge_dst, int* __restrict__ cursor,
                               int* __restrict__ perm) {
    int e = blockIdx.x * blockDim.x + threadIdx.x;
    if (e < NE_E) {
        int pos = atomicAdd(&cursor[edge_dst[e]], 1);
        perm[pos] = e;
    }
}

// ================= fused dual LayerNorm + GEMM (64->64), bf16 output =================
__global__ void node_proj2_kernel(const void* __restrict__ src_f, const void* __restrict__ dst_f,
                                  const void* __restrict__ lnw_s, const void* __restrict__ lnb_s,
                                  const void* __restrict__ W_s,
                                  const void* __restrict__ lnw_d, const void* __restrict__ lnb_d,
                                  const void* __restrict__ W_d, const void* __restrict__ b_d,
                                  const int* __restrict__ flagp,
                                  u16* __restrict__ ms, u16* __restrict__ md) {
    __shared__ u16 sW[C * C];          // packed: (k>>1)*128 + c*2 + (k&1)
    __shared__ float slnw[C], slnb[C], sbias[C];
    __shared__ float ybuf[4][C];

    const int isbf = *flagp;
    const int tid = threadIdx.x;
    const int half = gridDim.x >> 1;
    const int isrc = (blockIdx.x < half) ? 1 : 0;
    const void* xf  = isrc ? src_f : dst_f;
    const void* lnw = isrc ? lnw_s : lnw_d;
    const void* lnb = isrc ? lnb_s : lnb_d;
    const void* W   = isrc ? W_s : W_d;
    u16* out        = isrc ? ms : md;
    const int N     = isrc ? NS_N : ND_N;
    const int bid   = isrc ? blockIdx.x : blockIdx.x - half;
    const int nb    = isrc ? half : gridDim.x - half;

    for (int i = tid; i < C * C; i += blockDim.x) {
        int k = i >> 6, c = i & 63;
        sW[((k >> 1) << 7) + (c << 1) + (k & 1)] = loadb(W, i, isbf);
    }
    if (tid < C) {
        slnw[tid] = loadf(lnw, tid, isbf);
        slnb[tid] = loadf(lnb, tid, isbf);
        sbias[tid] = isrc ? 0.f : loadf(b_d, tid, isbf);
    }
    __syncthreads();

    const int wave = tid >> 6, lane = tid & 63;
    const u32* w = (const u32*)sW;
    const int gw = bid * 4 + wave, nw = nb * 4;
    for (int n = gw; n < N; n += nw) {
        float x = loadf(xf, (size_t)n * C + lane, isbf);
        float mean = waveAllSum(x) * (1.f / 64.f);
        float xc = x - mean;
        float var = waveAllSum(xc * xc) * (1.f / 64.f);
        float y = xc * rsqrtf(var + EPSV) * slnw[lane] + slnb[lane];
        WB();
        ybuf[wave][lane] = y;
        WB();
        float acc = sbias[lane];
        #pragma unroll 8
        for (int k2 = 0; k2 < 32; ++k2) {
            float2 yv = *(const float2*)&ybuf[wave][k2 * 2];
            u32 wp = w[(k2 << 6) + lane];
            acc += yv.x * lo16(wp) + yv.y * hi16(wp);
        }
        WB();
        out[(size_t)n * C + lane] = f2bbits(acc);
        WB();
    }
}

// ================= FAST PATH: MFMA edge kernel, perm-ordered, XOR-swizzled LDS ======
// R4 body (proven): bf16 ms/md gathers issued at body top (covered by GEMM1+ea),
// index-only depth-1 pipeline (eN/sN/ddN). Full operand prefetch spills (R2, R5).
__launch_bounds__(512, 4)
__global__ void edge_mfma_kernel(const void* __restrict__ edge_attr,
                                 const void* __restrict__ edge_scalars,
                                 const void* __restrict__ edge_logits,
                                 const int* __restrict__ edge_src,
                                 const int* __restrict__ edge_dst,
                                 const int* __restrict__ perm,
                                 const void* __restrict__ W_ea, const void* __restrict__ W_dtp,
                                 const void* __restrict__ W_r1, const void* __restrict__ b_r1,
                                 const void* __restrict__ W_r2, const void* __restrict__ b_r2,
                                 const void* __restrict__ alpha_vec,
                                 const int* __restrict__ flagp,
                                 const u16* __restrict__ ms, const u16* __restrict__ md,
                                 u16* __restrict__ valbuf, float* __restrict__ logitsbuf) {
    // XOR-swizzled rows: element group g (8 u16) of row n stored at group g^(n&7)
    __shared__ u16 sWr1T[C * SD];        // 8 KB  [n=64][k=64]
    __shared__ u16 sWr2T[2 * C * SD];    // 16 KB [n=128][k=64]
    __shared__ u16 sWdtpT[2 * C * C];    // 16 KB [n=128][k=64]
    __shared__ u16 sWeaT[C * 32];        // 4 KB  [n=64][k=32] linear (already conflict-min)
    __shared__ float sbr1[SD], sbr2[2 * C], salpha[C];
    __shared__ u16 scratch[8][2][16 * C];  // 32 KB, swizzled rows (per-wave)

    const int isbf = *flagp;
    const int tid = threadIdx.x;
    for (int i = tid; i < SD * SD; i += 512) {
        int k = i >> 6, n = i & 63;
        sWr1T[n * 64 + (((k >> 3) ^ (n & 7)) << 3) + (k & 7)] = loadb(W_r1, i, isbf);
    }
    for (int i = tid; i < SD * 2 * C; i += 512) {
        int k = i >> 7, n = i & 127;
        sWr2T[n * 64 + (((k >> 3) ^ (n & 7)) << 3) + (k & 7)] = loadb(W_r2, i, isbf);
    }
    for (int i = tid; i < C * 2 * C; i += 512) {
        int k = i >> 7, n = i & 127;
        sWdtpT[n * 64 + (((k >> 3) ^ (n & 7)) << 3) + (k & 7)] = loadb(W_dtp, i, isbf);
    }
    for (int i = tid; i < C * 32; i += 512) {
        int n = i >> 5, k = i & 31;
        sWeaT[i] = (k < AD) ? loadb(W_ea, (size_t)k * C + n, isbf) : (u16)0;
    }
    for (int i = tid; i < SD; i += 512) sbr1[i] = loadf(b_r1, i, isbf);
    for (int i = tid; i < 2 * C; i += 512) sbr2[i] = loadf(b_r2, i, isbf);
    for (int i = tid; i < C; i += 512) salpha[i] = loadf(alpha_vec, i, isbf);
    __syncthreads();

    const int wv = tid >> 6, lane = tid & 63;
    const int m15 = lane & 15, quad = lane >> 4;
    const int sw = m15 & 7;            // row&7 for rows indexed by m15 (weights n and tiles)
    const int pg0 = (quad ^ sw) << 3;  // physical byte-group offset for logical group quad
    const int pg1 = pg0 ^ 32;          // logical group quad+4
    u16* scr_r = scratch[wv][0];
    u16* scr_e = scratch[wv][1];

    const int NT = NE_E / 16;
    const int stride = gridDim.x * 8;
    int t = blockIdx.x * 8 + wv;

    // prologue: first tile's indices
    int e = 0, s = 0, dd = 0;
    if (t < NT) {
        e = perm[t * 16 + m15];
        s = edge_src[e];
        dd = edge_dst[e];
    }

    while (t < NT) {
        const int tn = t + stride;
        const int e0 = t * 16;
        // ---- current tile operand loads (e,s,dd known from rotation)
        short8 esA0 = load8bf(edge_scalars, (size_t)e * SD + quad * 8, isbf);
        short8 esA1 = load8bf(edge_scalars, (size_t)e * SD + 32 + quad * 8, isbf);
        float elg_lane = loadf(edge_logits, e, isbf);
        short8 eaA = 0;
        if (quad < 2) eaA = load8bf(edge_attr, (size_t)e * AD + quad * 8, isbf);
        // ---- bf16 gathers, in flight under GEMM1+ea phases
        const u16* msr = ms + (size_t)s * C;
        const u16* mdr = md + (size_t)dd * C;
        short8 gms0 = *(const short8*)&msr[quad * 8];
        short8 gms1 = *(const short8*)&msr[32 + quad * 8];
        short8 gmd0 = *(const short8*)&mdr[quad * 8];
        short8 gmd1 = *(const short8*)&mdr[32 + quad * 8];
        // ---- next tile's perm entry
        int eN = 0;
        if (tn < NT) eN = perm[tn * 16 + m15];
        WB();
        // ---- GEMM1: r = silu(es @ W_r1 + b) -> scr_r (swizzled [m][k])
        #pragma unroll
        for (int nt = 0; nt < 4; ++nt) {
            f32x4 c = {0.f, 0.f, 0.f, 0.f};
            c = MFMA16(esA0, *(const short8*)&sWr1T[(nt * 16 + m15) * 64 + pg0], c);
            c = MFMA16(esA1, *(const short8*)&sWr1T[(nt * 16 + m15) * 64 + pg1], c);
            float bc = sbr1[nt * 16 + m15];
            int lg = nt * 2 + (m15 >> 3);
            int o = m15 & 7;
            #pragma unroll
            for (int r = 0; r < 4; ++r) {
                float f = c[r] + bc;
                f = f / (1.f + __expf(-f));
                int row = quad * 4 + r;
                scr_r[row * 64 + ((lg ^ (row & 7)) << 3) + o] = f2bbits(f);
            }
        }
        // ---- ea = edge_attr @ W_ea -> scr_e (swizzled)
        #pragma unroll
        for (int nt = 0; nt < 4; ++nt) {
            f32x4 c = {0.f, 0.f, 0.f, 0.f};
            c = MFMA16(eaA, *(const short8*)&sWeaT[(nt * 16 + m15) * 32 + quad * 8], c);
            int lg = nt * 2 + (m15 >> 3);
            int o = m15 & 7;
            #pragma unroll
            for (int r = 0; r < 4; ++r) {
                int row = quad * 4 + r;
                scr_e[row * 64 + ((lg ^ (row & 7)) << 3) + o] = f2bbits(c[r]);
            }
        }
        // ---- next tile's src/dst (eN arrived under GEMM1)
        int sN = 0, ddN = 0;
        if (tn < NT) { sN = edge_src[eN]; ddN = edge_dst[eN]; }
        WB();
        short8 rA0 = *(const short8*)&scr_r[m15 * 64 + pg0];
        short8 rA1 = *(const short8*)&scr_r[m15 * 64 + pg1];
        short8 ev0 = *(const short8*)&scr_e[m15 * 64 + pg0];
        short8 ev1 = *(const short8*)&scr_e[m15 * 64 + pg1];
        short8 xA0, xA1;
        #pragma unroll
        for (int j = 0; j < 8; ++j) {
            float a = b2fu((u16)gms0[j]) + b2fu((u16)gmd0[j]);
            xA0[j] = (short)f2bbits(a * b2fu((u16)ev0[j]));
            float b = b2fu((u16)gms1[j]) + b2fu((u16)gmd1[j]);
            xA1[j] = (short)f2bbits(b * b2fu((u16)ev1[j]));
        }
        float elg_q[4];
        #pragma unroll
        for (int r = 0; r < 4; ++r) elg_q[r] = __shfl(elg_lane, quad * 4 + r, 64);
        WB();
        // ---- dual GEMM: w_edge & dtp over 8 N-tiles
        #pragma unroll
        for (int nt = 0; nt < 8; ++nt) {
            f32x4 w = {0.f, 0.f, 0.f, 0.f};
            w = MFMA16(rA0, *(const short8*)&sWr2T[(nt * 16 + m15) * 64 + pg0], w);
            w = MFMA16(rA1, *(const short8*)&sWr2T[(nt * 16 + m15) * 64 + pg1], w);
            f32x4 dv = {0.f, 0.f, 0.f, 0.f};
            dv = MFMA16(xA0, *(const short8*)&sWdtpT[(nt * 16 + m15) * 64 + pg0], dv);
            dv = MFMA16(xA1, *(const short8*)&sWdtpT[(nt * 16 + m15) * 64 + pg1], dv);
            float wb = sbr2[nt * 16 + m15];
            if (nt < 4) {
                float sa = salpha[nt * 16 + m15];
                #pragma unroll
                for (int r = 0; r < 4; ++r) {
                    float v = dv[r] * (w[r] + wb);
                    float lf = (v >= 0.f) ? v : 0.2f * v;
                    float tt = lf * sa;
                    tt += __shfl_xor(tt, 1, 64);
                    tt += __shfl_xor(tt, 2, 64);
                    tt += __shfl_xor(tt, 4, 64);
                    if ((lane & 7) == 0)
                        logitsbuf[(size_t)(e0 + quad * 4 + r) * NH + nt * 2 + ((lane >> 3) & 1)]
                            = tt + elg_q[r];
                }
            } else {
                int lg = (nt - 4) * 2 + (m15 >> 3);
                int o = m15 & 7;
                #pragma unroll
                for (int r = 0; r < 4; ++r) {
                    float v = dv[r] * (w[r] + wb);
                    int row = quad * 4 + r;
                    scr_r[row * 64 + ((lg ^ (row & 7)) << 3) + o] = f2bbits(v);
                }
            }
        }
        WB();
        // ---- coalesced val store (slot-ordered rows)
        {
            int row = lane >> 2, seg = lane & 3;
            int rw7 = row & 7;
            uint4 v0 = *(const uint4*)&scr_r[row * 64 + (((seg * 2) ^ rw7) << 3)];
            uint4 v1 = *(const uint4*)&scr_r[row * 64 + (((seg * 2 + 1) ^ rw7) << 3)];
            uint4* gp = (uint4*)&valbuf[(size_t)(e0 + row) * C + seg * 16];
            gp[0] = v0; gp[1] = v1;
        }
        WB();
        // ---- rotate
        t = tn; e = eN; s = sN; dd = ddN;
    }
}

// ================= aggregate: contiguous slots, 4-way unrolled online softmax =======
__global__ void aggregate_kernel(const int* __restrict__ row_ptr,
                                 const float* __restrict__ logitsbuf,
                                 const u16* __restrict__ valbuf,
                                 float* __restrict__ attout) {
    const int wave = threadIdx.x >> 6, lane = threadIdx.x & 63;
    const int head = lane >> 3;
    const int gw = blockIdx.x * 4 + wave, nw = gridDim.x * 4;
    for (int d = gw; d < ND_N; d += nw) {
        const int beg = row_ptr[d], end = row_ptr[d + 1];
        float m0 = -__builtin_inff(), z0 = 0.f, a0 = 0.f;
        float m1 = -__builtin_inff(), z1 = 0.f, a1 = 0.f;
        float m2 = -__builtin_inff(), z2 = 0.f, a2 = 0.f;
        float m3 = -__builtin_inff(), z3 = 0.f, a3 = 0.f;
        int i = beg;
        for (; i + 3 < end; i += 4) {
            float lg0 = logitsbuf[(size_t)i * NH + head];
            float lg1 = logitsbuf[(size_t)(i + 1) * NH + head];
            float lg2 = logitsbuf[(size_t)(i + 2) * NH + head];
            float lg3 = logitsbuf[(size_t)(i + 3) * NH + head];
            float v0 = b2fu(valbuf[(size_t)i * C + lane]);
            float v1 = b2fu(valbuf[(size_t)(i + 1) * C + lane]);
            float v2 = b2fu(valbuf[(size_t)(i + 2) * C + lane]);
            float v3 = b2fu(valbuf[(size_t)(i + 3) * C + lane]);
            float mn0 = fmaxf(m0, lg0);
            float mn1 = fmaxf(m1, lg1);
            float mn2 = fmaxf(m2, lg2);
            float mn3 = fmaxf(m3, lg3);
            float sc0 = __expf(m0 - mn0);
            float sc1 = __expf(m1 - mn1);
            float sc2 = __expf(m2 - mn2);
            float sc3 = __expf(m3 - mn3);
            float e0 = __expf(lg0 - mn0);
            float e1 = __expf(lg1 - mn1);
            float e2 = __expf(lg2 - mn2);
            float e3 = __expf(lg3 - mn3);
            z0 = z0 * sc0 + e0; a0 = a0 * sc0 + e0 * v0; m0 = mn0;
            z1 = z1 * sc1 + e1; a1 = a1 * sc1 + e1 * v1; m1 = mn1;
            z2 = z2 * sc2 + e2; a2 = a2 * sc2 + e2 * v2; m2 = mn2;
            z3 = z3 * sc3 + e3; a3 = a3 * sc3 + e3 * v3; m3 = mn3;
        }
        for (; i < end; ++i) {
            float lg0 = logitsbuf[(size_t)i * NH + head];
            float v0 = b2fu(valbuf[(size_t)i * C + lane]);
            float mn = fmaxf(m0, lg0);
            float sc = __expf(m0 - mn);
            float e0 = __expf(lg0 - mn);
            z0 = z0 * sc + e0; a0 = a0 * sc + e0 * v0; m0 = mn;
        }
        // merge the four chains (empty-chain safe: exp(-inf-finite)=0; all empty ->
        // z=nan -> (z>0) false -> writes 0)
        float ma = fmaxf(fmaxf(m0, m1), fmaxf(m2, m3));
        float s0 = __expf(m0 - ma), s1 = __expf(m1 - ma);
        float s2 = __expf(m2 - ma), s3 = __expf(m3 - ma);
        float z = z0 * s0 + z1 * s1 + z2 * s2 + z3 * s3;
        float acc = a0 * s0 + a1 * s1 + a2 * s2 + a3 * s3;
        attout[(size_t)d * C + lane] = (z > 0.f) ? acc / z : 0.f;
    }
}

// ================= SLOW PATH edge kernel (fallback; bf16 ms/md) =====================
__global__ void edge_csr_kernel(const void* __restrict__ edge_attr,
                                const void* __restrict__ edge_scalars,
                                const void* __restrict__ edge_logits,
                                const int* __restrict__ edge_src,
                                const int* __restrict__ row_ptr, const int* __restrict__ perm,
                                const void* __restrict__ W_ea, const void* __restrict__ W_dtp,
                                const void* __restrict__ W_r1, const void* __restrict__ b_r1,
                                const void* __restrict__ W_r2, const void* __restrict__ b_r2,
                                const void* __restrict__ alpha_vec,
                                const int* __restrict__ flagp,
                                const u16* __restrict__ ms, const u16* __restrict__ md,
                                float* __restrict__ attout) {
    __shared__ u16 sWr1[SD * SD];
    __shared__ u16 sWr2[SD * 2 * C];
    __shared__ u16 sWdtp[C * 2 * C];
    __shared__ u16 sWea[AD * C];
    __shared__ float sbr1[SD], sbr2[2 * C], salpha[C];
    __shared__ float sbuf[4][2][C];

    const int isbf = *flagp;
    const int tid = threadIdx.x;
    {
        for (int i = tid; i < SD * SD; i += blockDim.x) {
            int k = i >> 6, c = i & 63;
            sWr1[((k >> 1) << 7) + (c << 1) + (k & 1)] = loadb(W_r1, i, isbf);
        }
        for (int i = tid; i < SD * 2 * C; i += blockDim.x) {
            int k = i >> 7, c = i & 127;
            sWr2[(k << 7) + ((c & 63) << 1) + (c >> 6)] = loadb(W_r2, i, isbf);
        }
        for (int i = tid; i < C * 2 * C; i += blockDim.x) {
            int k = i >> 7, c = i & 127;
            sWdtp[(k << 7) + ((c & 63) << 1) + (c >> 6)] = loadb(W_dtp, i, isbf);
        }
        for (int i = tid; i < AD * C; i += blockDim.x) {
            int k = i >> 6, c = i & 63;
            sWea[((k >> 1) << 7) + (c << 1) + (k & 1)] = loadb(W_ea, i, isbf);
        }
        for (int i = tid; i < SD; i += blockDim.x) sbr1[i] = loadf(b_r1, i, isbf);
        for (int i = tid; i < 2 * C; i += blockDim.x) sbr2[i] = loadf(b_r2, i, isbf);
        for (int i = tid; i < C; i += blockDim.x) salpha[i] = loadf(alpha_vec, i, isbf);
    }
    __syncthreads();

    const int wave = tid >> 6, lane = tid & 63;
    float* buf0 = sbuf[wave][0];
    float* buf1 = sbuf[wave][1];
    const u32* wr1 = (const u32*)sWr1;
    const u32* wr2 = (const u32*)sWr2;
    const u32* wdtp = (const u32*)sWdtp;
    const u32* wea = (const u32*)sWea;
    const int gw = blockIdx.x * 4 + wave, nw = gridDim.x * 4;

    for (int d = gw; d < ND_N; d += nw) {
        const int beg = row_ptr[d], end = row_ptr[d + 1];
        const float mdv = b2fu(md[(size_t)d * C + lane]);
        float m = -__builtin_inff(), z = 0.f, acc = 0.f;

        for (int i = beg; i < end; ++i) {
            const int e = perm[i];
            WB();
            buf0[lane] = loadf(edge_scalars, (size_t)e * SD + lane, isbf);
            WB();
            float accr = sbr1[lane];
            #pragma unroll 8
            for (int k2 = 0; k2 < 32; ++k2) {
                float2 xv = *(const float2*)&buf0[k2 * 2];
                u32 wp = wr1[(k2 << 6) + lane];
                accr += xv.x * lo16(wp) + xv.y * hi16(wp);
            }
            float r = accr / (1.f + __expf(-accr));
            WB();
            buf1[lane] = r;
            WB();
            float we0 = sbr2[lane], we1 = sbr2[lane + C];
            #pragma unroll 8
            for (int k = 0; k < SD; ++k) {
                float rk = buf1[k];
                u32 wp = wr2[(k << 6) + lane];
                we0 += rk * lo16(wp);
                we1 += rk * hi16(wp);
            }
            WB();
            if (lane < AD) buf0[lane] = loadf(edge_attr, (size_t)e * AD + lane, isbf);
            WB();
            float eav = 0.f;
            #pragma unroll
            for (int k2 = 0; k2 < 8; ++k2) {
                float2 xv = *(const float2*)&buf0[k2 * 2];
                u32 wp = wea[(k2 << 6) + lane];
                eav += xv.x * lo16(wp) + xv.y * hi16(wp);
            }
            const int s = edge_src[e];
            float x = (b2fu(ms[(size_t)s * C + lane]) + mdv) * eav;
            WB();
            buf1[lane] = x;
            WB();
            float dt0 = 0.f, dt1 = 0.f;
            #pragma unroll 8
            for (int k = 0; k < C; ++k) {
                float xk = buf1[k];
                u32 wp = wdtp[(k << 6) + lane];
                dt0 += xk * lo16(wp);
                dt1 += xk * hi16(wp);
            }
            dt0 *= we0;
            dt1 *= we1;
            float lf = (dt0 >= 0.f) ? dt0 : 0.2f * dt0;
            float t = lf * salpha[lane];
            t += __shfl_xor(t, 1, 64);
            t += __shfl_xor(t, 2, 64);
            t += __shfl_xor(t, 4, 64);
            float lg = t + loadf(edge_logits, e, isbf);
            float mn = fmaxf(m, lg);
            float sc = __expf(m - mn);
            float a = __expf(lg - mn);
            z = z * sc + a;
            acc = acc * sc + a * dt1;
            m = mn;
        }
        attout[(size_t)d * C + lane] = (z > 0.f) ? acc / z : 0.f;
    }
}

// ================= FAST PATH final: MFMA epilogue (16 nodes / wave-tile) ============
// 8-wave blocks: weights shared by 8 waves, 1 block/CU but 8 waves/CU.
__launch_bounds__(512, 2)
__global__ void final_mfma_kernel(const void* __restrict__ dst_f,
                                  const float* __restrict__ attout,
                                  const void* __restrict__ W_proj, const void* __restrict__ b_proj,
                                  const void* __restrict__ ln_w, const void* __restrict__ ln_b,
                                  const void* __restrict__ W_f1, const void* __restrict__ b_f1,
                                  const void* __restrict__ W_f2, const void* __restrict__ b_f2,
                                  const int* __restrict__ flagp,
                                  void* __restrict__ out) {
    // XOR-swizzled weight rows (group g of row n at g^(n&7))
    __shared__ u16 sWpT[C * C];         // 8 KB   [n=64][k=64]
    __shared__ u16 sWf1T[MF * C];       // 24 KB  [n=192][k=64]
    __shared__ u16 sWf2T[C * MF];       // 24 KB  [n=64][k=192]
    __shared__ float sbp[C], slnw[C], slnb[C], sbf1[MF], sbf2[C];
    __shared__ uint4 scr4[8][400];      // 6400 B per wave, phase-aliased scratch

    const int isbf = *flagp;
    const int tid = threadIdx.x;       // blockDim = 512 (8 waves)
    for (int i = tid; i < C * C; i += 512) {
        int k = i >> 6, n = i & 63;
        sWpT[n * 64 + (((k >> 3) ^ (n & 7)) << 3) + (k & 7)] = loadb(W_proj, i, isbf);
    }
    for (int i = tid; i < C * MF; i += 512) {
        int k = i / MF, n = i - k * MF;     // W_f1[k][n], n<192
        sWf1T[n * 64 + (((k >> 3) ^ (n & 7)) << 3) + (k & 7)] = loadb(W_f1, i, isbf);
    }
    for (int i = tid; i < MF * C; i += 512) {
        int k = i >> 6, n = i & 63;         // W_f2[k][n], k<192
        sWf2T[n * 192 + (((k >> 3) ^ (n & 7)) << 3) + (k & 7)] = loadb(W_f2, i, isbf);
    }
    for (int i = tid; i < C; i += 512) {
        sbp[i] = loadf(b_proj, i, isbf);
        slnw[i] = loadf(ln_w, i, isbf);
        slnb[i] = loadf(ln_b, i, isbf);
        sbf2[i] = loadf(b_f2, i, isbf);
    }
    for (int i = tid; i < MF; i += 512) sbf1[i] = loadf(b_f1, i, isbf);
    __syncthreads();

    const int wv = tid >> 6, lane = tid & 63;
    const int m15 = lane & 15, quad = lane >> 4;
    const int sw = m15 & 7;
    const int pg0 = (quad ^ sw) << 3;
    const int pg1 = pg0 ^ 32;
    u16* scr = (u16*)scr4[wv];
    float* scrf = (float*)scr4[wv];

    for (int t = blockIdx.x * 8 + wv; t < ND_N / 16; t += gridDim.x * 8) {
        const int n0 = t * 16;
        short8 oA0 = load8bf(attout, (size_t)(n0 + m15) * C + quad * 8, 0);
        short8 oA1 = load8bf(attout, (size_t)(n0 + m15) * C + 32 + quad * 8, 0);
        float emb[4][4];
        #pragma unroll
        for (int nt = 0; nt < 4; ++nt) {
            f32x4 c = {0.f, 0.f, 0.f, 0.f};
            c = MFMA16(oA0, *(const short8*)&sWpT[(nt * 16 + m15) * 64 + pg0], c);
            c = MFMA16(oA1, *(const short8*)&sWpT[(nt * 16 + m15) * 64 + pg1], c);
            int col = nt * 16 + m15;
            float bp = sbp[col];
            #pragma unroll
            for (int r = 0; r < 4; ++r)
                emb[nt][r] = c[r] + bp + loadf(dst_f, (size_t)(n0 + quad * 4 + r) * C + col, isbf);
        }
        float y[4][4];
        #pragma unroll
        for (int r = 0; r < 4; ++r) {
            float part = emb[0][r] + emb[1][r] + emb[2][r] + emb[3][r];
            part += __shfl_xor(part, 1, 64);
            part += __shfl_xor(part, 2, 64);
            part += __shfl_xor(part, 4, 64);
            part += __shfl_xor(part, 8, 64);
            float mean = part * (1.f / 64.f);
            float q = 0.f;
            #pragma unroll
            for (int nt = 0; nt < 4; ++nt) {
                float d = emb[nt][r] - mean;
                q += d * d;
            }
            q += __shfl_xor(q, 1, 64);
            q += __shfl_xor(q, 2, 64);
            q += __shfl_xor(q, 4, 64);
            q += __shfl_xor(q, 8, 64);
            float rs = rsqrtf(q * (1.f / 64.f) + EPSV);
            #pragma unroll
            for (int nt = 0; nt < 4; ++nt) {
                int col = nt * 16 + m15;
                y[nt][r] = (emb[nt][r] - mean) * rs * slnw[col] + slnb[col];
            }
        }
        WB();
        #pragma unroll
        for (int nt = 0; nt < 4; ++nt)
            #pragma unroll
            for (int r = 0; r < 4; ++r)
                scr[(quad * 4 + r) * 72 + nt * 16 + m15] = f2bbits(y[nt][r]);
        WB();
        short8 yA0 = *(const short8*)&scr[m15 * 72 + quad * 8];
        short8 yA1 = *(const short8*)&scr[m15 * 72 + 32 + quad * 8];
        WB();
        #pragma unroll
        for (int nt = 0; nt < 12; ++nt) {
            f32x4 g = {0.f, 0.f, 0.f, 0.f};
            g = MFMA16(yA0, *(const short8*)&sWf1T[(nt * 16 + m15) * 64 + pg0], g);
            g = MFMA16(yA1, *(const short8*)&sWf1T[(nt * 16 + m15) * 64 + pg1], g);
            int col = nt * 16 + m15;
            float bg = sbf1[col];
            #pragma unroll
            for (int r = 0; r < 4; ++r) {
                float f = g[r] + bg;
                f = f / (1.f + __expf(-f));
                scr[(quad * 4 + r) * 200 + col] = f2bbits(f);
            }
        }
        WB();
        short8 gA[6];
        #pragma unroll
        for (int j = 0; j < 6; ++j)
            gA[j] = *(const short8*)&scr[m15 * 200 + j * 32 + quad * 8];
        WB();
        #pragma unroll
        for (int nt = 0; nt < 4; ++nt) {
            f32x4 c = {0.f, 0.f, 0.f, 0.f};
            #pragma unroll
            for (int j = 0; j < 6; ++j) {
                int lg = j * 4 + quad;           // logical group in 24-group row
                int pg = (lg ^ sw) << 3;         // n&7 = m15&7 = sw
                c = MFMA16(gA[j], *(const short8*)&sWf2T[(nt * 16 + m15) * 192 + pg], c);
            }
            int col = nt * 16 + m15;
            float bf = sbf2[col];
            #pragma unroll
            for (int r = 0; r < 4; ++r)
                scrf[(quad * 4 + r) * 68 + col] = c[r] + bf + emb[nt][r];
        }
        WB();
        {
            int row = lane >> 2, seg = lane & 3;
            if (isbf) {
                u16* gp = (u16*)out + (size_t)(n0 + row) * C + seg * 16;
                #pragma unroll
                for (int j = 0; j < 4; ++j) {
                    float4 v = *(const float4*)&scrf[row * 68 + seg * 16 + j * 4];
                    u32 p0 = (u32)f2bbits(v.x) | ((u32)f2bbits(v.y) << 16);
                    u32 p1 = (u32)f2bbits(v.z) | ((u32)f2bbits(v.w) << 16);
                    uint2 pk = {p0, p1};
                    *(uint2*)(gp + j * 4) = pk;
                }
            } else {
                float* gp = (float*)out + (size_t)(n0 + row) * C + seg * 16;
                #pragma unroll
                for (int j = 0; j < 4; ++j)
                    *(float4*)(gp + j * 4) = *(const float4*)&scrf[row * 68 + seg * 16 + j * 4];
            }
        }
        WB();
    }
}

// ================= SLOW PATH final (scalar) ========================================
__global__ void final_scalar_kernel(const void* __restrict__ dst_f,
                                    const float* __restrict__ attout,
                                    const void* __restrict__ W_proj, const void* __restrict__ b_proj,
                                    const void* __restrict__ ln_w, const void* __restrict__ ln_b,
                                    const void* __restrict__ W_f1, const void* __restrict__ b_f1,
                                    const void* __restrict__ W_f2, const void* __restrict__ b_f2,
                                    const int* __restrict__ flagp,
                                    void* __restrict__ out) {
    __shared__ u16 sWp[C * C];
    __shared__ u16 sWf1p[C * 2 * C];
    __shared__ u16 sWf1c[C * C];
    __shared__ u16 sWf2[MF * C];
    __shared__ float sbp[C], slnw[C], slnb[C], sbf1[MF], sbf2[C];
    __shared__ float ybuf[4][C];
    __shared__ float gbuf[4][MF];

    const int isbf = *flagp;
    const int tid = threadIdx.x;
    {
        for (int i = tid; i < C * C; i += blockDim.x) {
            int k = i >> 6, c = i & 63;
            sWp[((k >> 1) << 7) + (c << 1) + (k & 1)] = loadb(W_proj, i, isbf);
        }
        for (int i = tid; i < C * MF; i += blockDim.x) {
            int k = i / MF, c = i - k * MF;
            u16 b = loadb(W_f1, i, isbf);
            if (c < 128) sWf1p[(k << 7) + ((c & 63) << 1) + (c >> 6)] = b;
            else         sWf1c[(k << 6) + (c - 128)] = b;
        }
        for (int i = tid; i < MF * C; i += blockDim.x) {
            int k = i >> 6, c = i & 63;
            sWf2[((k >> 1) << 7) + (c << 1) + (k & 1)] = loadb(W_f2, i, isbf);
        }
        for (int i = tid; i < C; i += blockDim.x) {
            sbp[i] = loadf(b_proj, i, isbf);
            slnw[i] = loadf(ln_w, i, isbf);
            slnb[i] = loadf(ln_b, i, isbf);
            sbf2[i] = loadf(b_f2, i, isbf);
        }
        for (int i = tid; i < MF; i += blockDim.x) sbf1[i] = loadf(b_f1, i, isbf);
    }
    __syncthreads();

    const int wave = tid >> 6, lane = tid & 63;
    const u32* wp32 = (const u32*)sWp;
    const u32* wf1 = (const u32*)sWf1p;
    const u32* wf2 = (const u32*)sWf2;
    const int gw = blockIdx.x * 4 + wave, nw = gridDim.x * 4;

    for (int n = gw; n < ND_N; n += nw) {
        float o = attout[(size_t)n * C + lane];
        WB();
        ybuf[wave][lane] = o;
        WB();
        float p = sbp[lane];
        #pragma unroll 8
        for (int k2 = 0; k2 < 32; ++k2) {
            float2 yv = *(const float2*)&ybuf[wave][k2 * 2];
            u32 wv = wp32[(k2 << 6) + lane];
            p += yv.x * lo16(wv) + yv.y * hi16(wv);
        }
        float emb = p + loadf(dst_f, (size_t)n * C + lane, isbf);
        float mean = waveAllSum(emb) * (1.f / 64.f);
        float ec = emb - mean;
        float var = waveAllSum(ec * ec) * (1.f / 64.f);
        float y = ec * rsqrtf(var + EPSV) * slnw[lane] + slnb[lane];
        WB();
        ybuf[wave][lane] = y;
        WB();
        float g0 = sbf1[lane], g1v = sbf1[lane + C], g2v = sbf1[lane + 2 * C];
        #pragma unroll 8
        for (int k = 0; k < C; ++k) {
            float yk = ybuf[wave][k];
            u32 wv = wf1[(k << 6) + lane];
            union { u32 u; float f; } cv; cv.u = ((u32)sWf1c[(k << 6) + lane]) << 16;
            g0 += yk * lo16(wv);
            g1v += yk * hi16(wv);
            g2v += yk * cv.f;
        }
        WB();
        gbuf[wave][lane] = g0 / (1.f + __expf(-g0));
        gbuf[wave][lane + C] = g1v / (1.f + __expf(-g1v));
        gbuf[wave][lane + 2 * C] = g2v / (1.f + __expf(-g2v));
        WB();
        float f = sbf2[lane];
        #pragma unroll 8
        for (int k2 = 0; k2 < 96; ++k2) {
            float2 gv = *(const float2*)&gbuf[wave][k2 * 2];
            u32 wv = wf2[(k2 << 6) + lane];
            f += gv.x * lo16(wv) + gv.y * hi16(wv);
        }
        WB();
        float res = f + emb;
        if (isbf) ((bf16*)out)[(size_t)n * C + lane] = __float2bfloat16(res);
        else      ((float*)out)[(size_t)n * C + lane] = res;
    }
}

extern "C" void kernel_launch(void* const* d_in, const int* in_sizes, int n_in,
                              void* d_out, int out_size, void* d_ws, size_t ws_size,
                              hipStream_t stream) {
    const void* src_f        = d_in[0];
    const void* dst_f        = d_in[1];
    const void* edge_attr    = d_in[2];
    const void* edge_scalars = d_in[3];
    const void* edge_logits  = d_in[4];
    const int*  edge_src     = (const int*)d_in[5];
    const int*  edge_dst     = (const int*)d_in[6];
    const void* ln_src_w = d_in[7];
    const void* ln_src_b = d_in[8];
    const void* W_src    = d_in[9];
    const void* ln_dst_w = d_in[10];
    const void* ln_dst_b = d_in[11];
    const void* W_dst    = d_in[12];
    const void* b_dst    = d_in[13];
    const void* W_ea     = d_in[14];
    const void* W_dtp    = d_in[15];
    const void* W_r1     = d_in[16];
    const void* b_r1     = d_in[17];
    const void* W_r2     = d_in[18];
    const void* b_r2     = d_in[19];
    const void* alpha_vec = d_in[20];
    const void* W_proj   = d_in[21];
    const void* b_proj   = d_in[22];
    const void* ln_post_w = d_in[23];
    const void* ln_post_b = d_in[24];
    const void* W_f1     = d_in[25];
    const void* b_f1     = d_in[26];
    const void* W_f2     = d_in[27];
    const void* b_f2     = d_in[28];

    // ---- workspace layout (ms/md regions sized for fp32 but hold bf16 content;
    //      ms region reused as fp32 attout after the edge kernel) ----
    int* flag     = (int*)d_ws;                         // 16 ints
    float* msf    = (float*)d_ws + 16;                  // NS*C fp32-sized region
    float* mdf    = msf + (size_t)NS_N * C;             // ND*C fp32-sized region
    u16* ms16     = (u16*)msf;
    u16* md16     = (u16*)mdf;
    int* cnt      = (int*)(mdf + (size_t)ND_N * C);     // ND
    int* row_ptr  = cnt + ND_N;                         // ND+1 (padded)
    int* cursor   = row_ptr + (ND_N + 4);               // ND
    int* perm     = cursor + ND_N;                      // E
    float* logitsbuf = (float*)(perm + NE_E);           // fast: E*NH (slot-indexed)
    u16* valbuf      = (u16*)(logitsbuf + (size_t)NE_E * NH); // fast: E*C bf16 (slot-indexed)
    float* attout_slow = (float*)(perm + NE_E);         // slow: ND*C (aliases logitsbuf)

    size_t base_b = (size_t)(16 + NS_N * C + ND_N * C) * 4
                  + ((size_t)ND_N * 3 + 4 + NE_E) * 4;
    size_t need_fast = base_b + (size_t)NE_E * NH * 4 + (size_t)NE_E * C * 2;
    size_t need_slow = base_b + (size_t)ND_N * C * 4;
    int fast = (ws_size >= need_fast) ? 1 : 0;
    if (!fast && ws_size < need_slow) return;

    // detect + cnt-zero fused
    detect_zero_kernel<<<1 + (ND_N + 255) / 256, 256, 0, stream>>>(src_f, flag, cnt);
    hist_kernel<<<(NE_E + 255) / 256, 256, 0, stream>>>(edge_dst, cnt);
    scan_phase1<<<SCAN_NCH, 256, 0, stream>>>(cnt, perm);
    scan_phase3<<<SCAN_NCH, 256, 0, stream>>>(cnt, perm, row_ptr, cursor, &row_ptr[ND_N]);
    scatter_kernel<<<(NE_E + 255) / 256, 256, 0, stream>>>(edge_dst, cursor, perm);

    // fused dual node projection (bf16 outputs)
    node_proj2_kernel<<<2048, 256, 0, stream>>>(src_f, dst_f,
                                                ln_src_w, ln_src_b, W_src,
                                                ln_dst_w, ln_dst_b, W_dst, b_dst,
                                                flag, ms16, md16);

    if (fast) {
        edge_mfma_kernel<<<1024, 512, 0, stream>>>(edge_attr, edge_scalars, edge_logits,
                                                   edge_src, edge_dst, perm,
                                                   W_ea, W_dtp, W_r1, b_r1, W_r2, b_r2,
                                                   alpha_vec, flag, ms16, md16,
                                                   valbuf, logitsbuf);
        // ms region dead after edge kernel -> reuse as fp32 attout
        aggregate_kernel<<<4096, 256, 0, stream>>>(row_ptr, logitsbuf, valbuf, msf);
        final_mfma_kernel<<<256, 512, 0, stream>>>(dst_f, msf,
                                                   W_proj, b_proj, ln_post_w, ln_post_b,
                                                   W_f1, b_f1, W_f2, b_f2,
                                                   flag, d_out);
    } else {
        edge_csr_kernel<<<2048, 256, 0, stream>>>(edge_attr, edge_scalars, edge_logits,
                                                  edge_src, row_ptr, perm,
                                                  W_ea, W_dtp, W_r1, b_r1, W_r2, b_r2,
                                                  alpha_vec, flag, ms16, md16, attout_slow);
        final_scalar_kernel<<<1024, 256, 0, stream>>>(dst_f, attout_slow,
                                                      W_proj, b_proj, ln_post_w, ln_post_b,
                                                      W_f1, b_f1, W_f2, b_f2,
                                                      flag, d_out);
    }
}

// Round 7
// 575.177 us; speedup vs baseline: 1.1219x; 1.0498x over previous
//
#include <hip/hip_runtime.h>
#include <hip/hip_bf16.h>

typedef __hip_bfloat16 bf16;
typedef unsigned short u16;
typedef unsigned int u32;

#define NS_N 50000
#define ND_N 50000
#define NE_E 600000
#define C 64
#define AD 16
#define SD 64
#define NH 8
#define MF 192
#define EPSV 1e-5f

#define WB() __builtin_amdgcn_wave_barrier()

typedef short short8 __attribute__((ext_vector_type(8)));
typedef float f32x4 __attribute__((ext_vector_type(4)));
#define MFMA16(a, b, c) __builtin_amdgcn_mfma_f32_16x16x32_bf16(a, b, c, 0, 0, 0)

__device__ __forceinline__ float lo16(u32 u) {
    union { u32 i; float f; } v; v.i = u << 16; return v.f;
}
__device__ __forceinline__ float hi16(u32 u) {
    union { u32 i; float f; } v; v.i = u & 0xffff0000u; return v.f;
}
__device__ __forceinline__ float b2fu(u16 u) {
    union { u32 i; float f; } v; v.i = ((u32)u) << 16; return v.f;
}
__device__ __forceinline__ u16 f2bbits(float f) {   // RNE fp32->bf16 bits
    u32 u = __float_as_uint(f);
    u32 r = u + 0x7FFFu + ((u >> 16) & 1u);
    return (u16)(r >> 16);
}
// dtype-adaptive loads: isbf==1 -> buffer is bf16, else fp32
__device__ __forceinline__ float loadf(const void* p, size_t i, int isbf) {
    if (isbf) { union { u32 u; float f; } v; v.u = ((u32)((const u16*)p)[i]) << 16; return v.f; }
    return ((const float*)p)[i];
}
__device__ __forceinline__ u16 loadb(const void* p, size_t i, int isbf) {
    if (isbf) return ((const u16*)p)[i];
    return f2bbits(((const float*)p)[i]);
}
__device__ __forceinline__ short8 load8bf(const void* p, size_t off, int isbf) {
    if (isbf) return *(const short8*)((const u16*)p + off);
    const float4* q = (const float4*)((const float*)p + off);
    float4 f0 = q[0], f1 = q[1];
    short8 r;
    r[0] = (short)f2bbits(f0.x); r[1] = (short)f2bbits(f0.y);
    r[2] = (short)f2bbits(f0.z); r[3] = (short)f2bbits(f0.w);
    r[4] = (short)f2bbits(f1.x); r[5] = (short)f2bbits(f1.y);
    r[6] = (short)f2bbits(f1.z); r[7] = (short)f2bbits(f1.w);
    return r;
}

__device__ __forceinline__ float waveAllSum(float v) {
    #pragma unroll
    for (int off = 32; off >= 1; off >>= 1) v += __shfl_xor(v, off, 64);
    return v;
}

// ================= dtype detection + cnt zero (fused) =================
__global__ void detect_zero_kernel(const void* src, int* flag, int* cnt) {
    if (blockIdx.x == 0) {
        if (threadIdx.x < 64) {
            const u16* p = (const u16*)src;
            const int lane = threadIdx.x;
            int c = 0;
            #pragma unroll
            for (int j = 0; j < 32; ++j) {
                u16 w = p[(size_t)(lane * 32 + j) * 2];
                int e = (w >> 7) & 0xFF;
                if (w == 0 || (e >= 100 && e <= 150)) c++;
            }
            #pragma unroll
            for (int off = 32; off >= 1; off >>= 1) c += __shfl_xor(c, off, 64);
            if (lane == 0) *flag = (c > 1536) ? 1 : 0;
        }
    } else {
        int i = (blockIdx.x - 1) * blockDim.x + threadIdx.x;
        if (i < ND_N) cnt[i] = 0;
    }
}

// ================= CSR build =================
__global__ void hist_kernel(const int* __restrict__ edge_dst, int* __restrict__ cnt) {
    int e = blockIdx.x * blockDim.x + threadIdx.x;
    if (e < NE_E) atomicAdd(&cnt[edge_dst[e]], 1);
}

// ---- 2-phase parallel scan (chunk sums -> per-chunk scan w/ inline chunk-prefix) ----
#define SCAN_CHUNK 1024
#define SCAN_NCH ((ND_N + SCAN_CHUNK - 1) / SCAN_CHUNK)   // 49 (must be <= 64)

__global__ void scan_phase1(const int* __restrict__ cnt, int* __restrict__ chunksum) {
    __shared__ int wsum[4];
    const int b = blockIdx.x, tidx = threadIdx.x;    // 256 threads
    const int base = b * SCAN_CHUNK + tidx * 4;
    int s = 0;
    if (base + 3 < ND_N) {
        int4 v = *(const int4*)&cnt[base];
        s = v.x + v.y + v.z + v.w;
    } else {
        #pragma unroll
        for (int j = 0; j < 4; ++j) { int i = base + j; if (i < ND_N) s += cnt[i]; }
    }
    #pragma unroll
    for (int off = 32; off >= 1; off >>= 1) s += __shfl_xor(s, off, 64);
    const int wv = tidx >> 6, lane = tidx & 63;
    if (lane == 0) wsum[wv] = s;
    __syncthreads();
    if (tidx == 0) chunksum[b] = wsum[0] + wsum[1] + wsum[2] + wsum[3];
}

// phase3 with inlined chunk-offset scan (first wave recomputes the 49-entry prefix)
__global__ void scan_phase3(const int* __restrict__ cnt, const int* __restrict__ chunksum,
                            int* __restrict__ row_ptr, int* __restrict__ cursor,
                            int* __restrict__ row_ptr_last) {
    __shared__ int woff[4];
    __shared__ int choff_s;
    const int b = blockIdx.x, tidx = threadIdx.x;    // 256 threads
    if (tidx < 64) {
        int v = (tidx < SCAN_NCH) ? chunksum[tidx] : 0;
        int incl = v;
        #pragma unroll
        for (int off = 1; off < 64; off <<= 1) {
            int t = __shfl_up(incl, off, 64);
            if (tidx >= off) incl += t;
        }
        if (tidx == b) choff_s = incl - v;           // exclusive prefix for this chunk
        if (b == 0 && tidx == 63) *row_ptr_last = incl;  // grand total
    }
    const int base = b * SCAN_CHUNK + tidx * 4;
    int v[4];
    #pragma unroll
    for (int j = 0; j < 4; ++j) { int i = base + j; v[j] = (i < ND_N) ? cnt[i] : 0; }
    int s = v[0] + v[1] + v[2] + v[3];
    int incl = s;
    const int lane = tidx & 63, wv = tidx >> 6;
    #pragma unroll
    for (int off = 1; off < 64; off <<= 1) {
        int t = __shfl_up(incl, off, 64);
        if (lane >= off) incl += t;
    }
    if (lane == 63) woff[wv] = incl;
    __syncthreads();
    int cross = 0;
    for (int w = 0; w < wv; ++w) cross += woff[w];
    int run = choff_s + cross + (incl - s);
    #pragma unroll
    for (int j = 0; j < 4; ++j) {
        int i = base + j;
        if (i < ND_N) { row_ptr[i] = run; cursor[i] = run; }
        run += v[j];
    }
}

__global__ void scatter_kernel(const int* __restrict__ edge_dst, int* __restrict__ cursor,
                               int* __restrict__ perm) {
    int e = blockIdx.x * blockDim.x + threadIdx.x;
    if (e < NE_E) {
        int pos = atomicAdd(&cursor[edge_dst[e]], 1);
        perm[pos] = e;
    }
}

// ================= fused dual LayerNorm + GEMM (64->64) via MFMA, bf16 output =======
// 16 nodes per wave-tile; same fragment layout + swizzled-weight + scratch-store
// patterns as edge_mfma (verified there). LN: 2 shuffles (xor 16/32 over quad groups).
__launch_bounds__(512)
__global__ void node_proj2_mfma(const void* __restrict__ src_f, const void* __restrict__ dst_f,
                                const void* __restrict__ lnw_s, const void* __restrict__ lnb_s,
                                const void* __restrict__ W_s,
                                const void* __restrict__ lnw_d, const void* __restrict__ lnb_d,
                                const void* __restrict__ W_d, const void* __restrict__ b_d,
                                const int* __restrict__ flagp,
                                u16* __restrict__ ms, u16* __restrict__ md) {
    __shared__ u16 sWT[2][C * C];        // 16 KB, XOR-swizzled W^T rows (n-major)
    __shared__ float slnw2[2][C], slnb2[2][C], sbias[C];
    __shared__ u16 scratch[8][16 * C];   // 16 KB, swizzled rows (per-wave)

    const int isbf = *flagp;
    const int tid = threadIdx.x;
    for (int i = tid; i < C * C; i += 512) {
        int k = i >> 6, n = i & 63;
        int off = n * 64 + (((k >> 3) ^ (n & 7)) << 3) + (k & 7);
        sWT[0][off] = loadb(W_s, i, isbf);
        sWT[1][off] = loadb(W_d, i, isbf);
    }
    for (int i = tid; i < C; i += 512) {
        slnw2[0][i] = loadf(lnw_s, i, isbf);
        slnb2[0][i] = loadf(lnb_s, i, isbf);
        slnw2[1][i] = loadf(lnw_d, i, isbf);
        slnb2[1][i] = loadf(lnb_d, i, isbf);
        sbias[i] = loadf(b_d, i, isbf);
    }
    __syncthreads();

    const int wv = tid >> 6, lane = tid & 63;
    const int m15 = lane & 15, quad = lane >> 4;
    const int sw = m15 & 7;
    const int pg0 = (quad ^ sw) << 3;
    const int pg1 = pg0 ^ 32;
    u16* scr = scratch[wv];

    const int HT = NS_N / 16;            // 3125 tiles per half
    const int NTILE = 2 * HT;
    for (int t = blockIdx.x * 8 + wv; t < NTILE; t += gridDim.x * 8) {
        const int half = (t >= HT) ? 1 : 0;
        const int n0 = (half ? (t - HT) : t) * 16;
        const void* xf = half ? dst_f : src_f;
        u16* out = half ? md : ms;
        // ---- load row n0+m15, channels quad*8..+8 and 32+quad*8..+8
        float x0[8], x1[8];
        {
            size_t base = (size_t)(n0 + m15) * C + quad * 8;
            if (isbf) {
                short8 aa = *(const short8*)((const u16*)xf + base);
                short8 bb = *(const short8*)((const u16*)xf + base + 32);
                #pragma unroll
                for (int j = 0; j < 8; ++j) {
                    x0[j] = b2fu((u16)aa[j]);
                    x1[j] = b2fu((u16)bb[j]);
                }
            } else {
                const float* xp = (const float*)xf + base;
                float4 a0 = *(const float4*)xp;
                float4 a1 = *(const float4*)(xp + 4);
                float4 b0 = *(const float4*)(xp + 32);
                float4 b1 = *(const float4*)(xp + 36);
                x0[0] = a0.x; x0[1] = a0.y; x0[2] = a0.z; x0[3] = a0.w;
                x0[4] = a1.x; x0[5] = a1.y; x0[6] = a1.z; x0[7] = a1.w;
                x1[0] = b0.x; x1[1] = b0.y; x1[2] = b0.z; x1[3] = b0.w;
                x1[4] = b1.x; x1[5] = b1.y; x1[6] = b1.z; x1[7] = b1.w;
            }
        }
        // ---- LayerNorm across the row (reduce over quad groups: xor 16, 32)
        float s = 0.f;
        #pragma unroll
        for (int j = 0; j < 8; ++j) s += x0[j] + x1[j];
        s += __shfl_xor(s, 16, 64);
        s += __shfl_xor(s, 32, 64);
        float mean = s * (1.f / 64.f);
        float q = 0.f;
        #pragma unroll
        for (int j = 0; j < 8; ++j) {
            float d0 = x0[j] - mean, d1 = x1[j] - mean;
            q += d0 * d0 + d1 * d1;
        }
        q += __shfl_xor(q, 16, 64);
        q += __shfl_xor(q, 32, 64);
        float rs = rsqrtf(q * (1.f / 64.f) + EPSV);
        short8 xA0, xA1;
        #pragma unroll
        for (int j = 0; j < 8; ++j) {
            int c0 = quad * 8 + j, c1 = 32 + quad * 8 + j;
            xA0[j] = (short)f2bbits((x0[j] - mean) * rs * slnw2[half][c0] + slnb2[half][c0]);
            xA1[j] = (short)f2bbits((x1[j] - mean) * rs * slnw2[half][c1] + slnb2[half][c1]);
        }
        WB();
        // ---- GEMM: y @ W (+ bias for dst half) -> swizzled scratch
        const u16* wT = sWT[half];
        #pragma unroll
        for (int nt = 0; nt < 4; ++nt) {
            f32x4 c = {0.f, 0.f, 0.f, 0.f};
            c = MFMA16(xA0, *(const short8*)&wT[(nt * 16 + m15) * 64 + pg0], c);
            c = MFMA16(xA1, *(const short8*)&wT[(nt * 16 + m15) * 64 + pg1], c);
            float bb = half ? sbias[nt * 16 + m15] : 0.f;
            int lg = nt * 2 + (m15 >> 3);
            int o = m15 & 7;
            #pragma unroll
            for (int r = 0; r < 4; ++r) {
                float v = c[r] + bb;
                int row = quad * 4 + r;
                scr[row * 64 + ((lg ^ (row & 7)) << 3) + o] = f2bbits(v);
            }
        }
        WB();
        // ---- coalesced bf16 store
        {
            int row = lane >> 2, seg = lane & 3;
            int rw7 = row & 7;
            uint4 v0 = *(const uint4*)&scr[row * 64 + (((seg * 2) ^ rw7) << 3)];
            uint4 v1 = *(const uint4*)&scr[row * 64 + (((seg * 2 + 1) ^ rw7) << 3)];
            uint4* gp = (uint4*)&out[(size_t)(n0 + row) * C + seg * 16];
            gp[0] = v0; gp[1] = v1;
        }
        WB();
    }
}

// ================= FAST PATH: MFMA edge kernel, perm-ordered, XOR-swizzled LDS ======
// R4 body (proven): bf16 ms/md gathers issued at body top (covered by GEMM1+ea),
// index-only depth-1 pipeline (eN/sN/ddN). Full operand prefetch spills (R2, R5).
__launch_bounds__(512, 4)
__global__ void edge_mfma_kernel(const void* __restrict__ edge_attr,
                                 const void* __restrict__ edge_scalars,
                                 const void* __restrict__ edge_logits,
                                 const int* __restrict__ edge_src,
                                 const int* __restrict__ edge_dst,
                                 const int* __restrict__ perm,
                                 const void* __restrict__ W_ea, const void* __restrict__ W_dtp,
                                 const void* __restrict__ W_r1, const void* __restrict__ b_r1,
                                 const void* __restrict__ W_r2, const void* __restrict__ b_r2,
                                 const void* __restrict__ alpha_vec,
                                 const int* __restrict__ flagp,
                                 const u16* __restrict__ ms, const u16* __restrict__ md,
                                 u16* __restrict__ valbuf, float* __restrict__ logitsbuf) {
    // XOR-swizzled rows: element group g (8 u16) of row n stored at group g^(n&7)
    __shared__ u16 sWr1T[C * SD];        // 8 KB  [n=64][k=64]
    __shared__ u16 sWr2T[2 * C * SD];    // 16 KB [n=128][k=64]
    __shared__ u16 sWdtpT[2 * C * C];    // 16 KB [n=128][k=64]
    __shared__ u16 sWeaT[C * 32];        // 4 KB  [n=64][k=32] linear (already conflict-min)
    __shared__ float sbr1[SD], sbr2[2 * C], salpha[C];
    __shared__ u16 scratch[8][2][16 * C];  // 32 KB, swizzled rows (per-wave)

    const int isbf = *flagp;
    const int tid = threadIdx.x;
    for (int i = tid; i < SD * SD; i += 512) {
        int k = i >> 6, n = i & 63;
        sWr1T[n * 64 + (((k >> 3) ^ (n & 7)) << 3) + (k & 7)] = loadb(W_r1, i, isbf);
    }
    for (int i = tid; i < SD * 2 * C; i += 512) {
        int k = i >> 7, n = i & 127;
        sWr2T[n * 64 + (((k >> 3) ^ (n & 7)) << 3) + (k & 7)] = loadb(W_r2, i, isbf);
    }
    for (int i = tid; i < C * 2 * C; i += 512) {
        int k = i >> 7, n = i & 127;
        sWdtpT[n * 64 + (((k >> 3) ^ (n & 7)) << 3) + (k & 7)] = loadb(W_dtp, i, isbf);
    }
    for (int i = tid; i < C * 32; i += 512) {
        int n = i >> 5, k = i & 31;
        sWeaT[i] = (k < AD) ? loadb(W_ea, (size_t)k * C + n, isbf) : (u16)0;
    }
    for (int i = tid; i < SD; i += 512) sbr1[i] = loadf(b_r1, i, isbf);
    for (int i = tid; i < 2 * C; i += 512) sbr2[i] = loadf(b_r2, i, isbf);
    for (int i = tid; i < C; i += 512) salpha[i] = loadf(alpha_vec, i, isbf);
    __syncthreads();

    const int wv = tid >> 6, lane = tid & 63;
    const int m15 = lane & 15, quad = lane >> 4;
    const int sw = m15 & 7;            // row&7 for rows indexed by m15 (weights n and tiles)
    const int pg0 = (quad ^ sw) << 3;  // physical byte-group offset for logical group quad
    const int pg1 = pg0 ^ 32;          // logical group quad+4
    u16* scr_r = scratch[wv][0];
    u16* scr_e = scratch[wv][1];

    const int NT = NE_E / 16;
    const int stride = gridDim.x * 8;
    int t = blockIdx.x * 8 + wv;

    // prologue: first tile's indices
    int e = 0, s = 0, dd = 0;
    if (t < NT) {
        e = perm[t * 16 + m15];
        s = edge_src[e];
        dd = edge_dst[e];
    }

    while (t < NT) {
        const int tn = t + stride;
        const int e0 = t * 16;
        // ---- current tile operand loads (e,s,dd known from rotation)
        short8 esA0 = load8bf(edge_scalars, (size_t)e * SD + quad * 8, isbf);
        short8 esA1 = load8bf(edge_scalars, (size_t)e * SD + 32 + quad * 8, isbf);
        float elg_lane = loadf(edge_logits, e, isbf);
        short8 eaA = 0;
        if (quad < 2) eaA = load8bf(edge_attr, (size_t)e * AD + quad * 8, isbf);
        // ---- bf16 gathers, in flight under GEMM1+ea phases
        const u16* msr = ms + (size_t)s * C;
        const u16* mdr = md + (size_t)dd * C;
        short8 gms0 = *(const short8*)&msr[quad * 8];
        short8 gms1 = *(const short8*)&msr[32 + quad * 8];
        short8 gmd0 = *(const short8*)&mdr[quad * 8];
        short8 gmd1 = *(const short8*)&mdr[32 + quad * 8];
        // ---- next tile's perm entry
        int eN = 0;
        if (tn < NT) eN = perm[tn * 16 + m15];
        WB();
        // ---- GEMM1: r = silu(es @ W_r1 + b) -> scr_r (swizzled [m][k])
        #pragma unroll
        for (int nt = 0; nt < 4; ++nt) {
            f32x4 c = {0.f, 0.f, 0.f, 0.f};
            c = MFMA16(esA0, *(const short8*)&sWr1T[(nt * 16 + m15) * 64 + pg0], c);
            c = MFMA16(esA1, *(const short8*)&sWr1T[(nt * 16 + m15) * 64 + pg1], c);
            float bc = sbr1[nt * 16 + m15];
            int lg = nt * 2 + (m15 >> 3);
            int o = m15 & 7;
            #pragma unroll
            for (int r = 0; r < 4; ++r) {
                float f = c[r] + bc;
                f = f / (1.f + __expf(-f));
                int row = quad * 4 + r;
                scr_r[row * 64 + ((lg ^ (row & 7)) << 3) + o] = f2bbits(f);
            }
        }
        // ---- ea = edge_attr @ W_ea -> scr_e (swizzled)
        #pragma unroll
        for (int nt = 0; nt < 4; ++nt) {
            f32x4 c = {0.f, 0.f, 0.f, 0.f};
            c = MFMA16(eaA, *(const short8*)&sWeaT[(nt * 16 + m15) * 32 + quad * 8], c);
            int lg = nt * 2 + (m15 >> 3);
            int o = m15 & 7;
            #pragma unroll
            for (int r = 0; r < 4; ++r) {
                int row = quad * 4 + r;
                scr_e[row * 64 + ((lg ^ (row & 7)) << 3) + o] = f2bbits(c[r]);
            }
        }
        // ---- next tile's src/dst (eN arrived under GEMM1)
        int sN = 0, ddN = 0;
        if (tn < NT) { sN = edge_src[eN]; ddN = edge_dst[eN]; }
        WB();
        short8 rA0 = *(const short8*)&scr_r[m15 * 64 + pg0];
        short8 rA1 = *(const short8*)&scr_r[m15 * 64 + pg1];
        short8 ev0 = *(const short8*)&scr_e[m15 * 64 + pg0];
        short8 ev1 = *(const short8*)&scr_e[m15 * 64 + pg1];
        short8 xA0, xA1;
        #pragma unroll
        for (int j = 0; j < 8; ++j) {
            float a = b2fu((u16)gms0[j]) + b2fu((u16)gmd0[j]);
            xA0[j] = (short)f2bbits(a * b2fu((u16)ev0[j]));
            float b = b2fu((u16)gms1[j]) + b2fu((u16)gmd1[j]);
            xA1[j] = (short)f2bbits(b * b2fu((u16)ev1[j]));
        }
        float elg_q[4];
        #pragma unroll
        for (int r = 0; r < 4; ++r) elg_q[r] = __shfl(elg_lane, quad * 4 + r, 64);
        WB();
        // ---- dual GEMM: w_edge & dtp over 8 N-tiles
        #pragma unroll
        for (int nt = 0; nt < 8; ++nt) {
            f32x4 w = {0.f, 0.f, 0.f, 0.f};
            w = MFMA16(rA0, *(const short8*)&sWr2T[(nt * 16 + m15) * 64 + pg0], w);
            w = MFMA16(rA1, *(const short8*)&sWr2T[(nt * 16 + m15) * 64 + pg1], w);
            f32x4 dv = {0.f, 0.f, 0.f, 0.f};
            dv = MFMA16(xA0, *(const short8*)&sWdtpT[(nt * 16 + m15) * 64 + pg0], dv);
            dv = MFMA16(xA1, *(const short8*)&sWdtpT[(nt * 16 + m15) * 64 + pg1], dv);
            float wb = sbr2[nt * 16 + m15];
            if (nt < 4) {
                float sa = salpha[nt * 16 + m15];
                #pragma unroll
                for (int r = 0; r < 4; ++r) {
                    float v = dv[r] * (w[r] + wb);
                    float lf = (v >= 0.f) ? v : 0.2f * v;
                    float tt = lf * sa;
                    tt += __shfl_xor(tt, 1, 64);
                    tt += __shfl_xor(tt, 2, 64);
                    tt += __shfl_xor(tt, 4, 64);
                    if ((lane & 7) == 0)
                        logitsbuf[(size_t)(e0 + quad * 4 + r) * NH + nt * 2 + ((lane >> 3) & 1)]
                            = tt + elg_q[r];
                }
            } else {
                int lg = (nt - 4) * 2 + (m15 >> 3);
                int o = m15 & 7;
                #pragma unroll
                for (int r = 0; r < 4; ++r) {
                    float v = dv[r] * (w[r] + wb);
                    int row = quad * 4 + r;
                    scr_r[row * 64 + ((lg ^ (row & 7)) << 3) + o] = f2bbits(v);
                }
            }
        }
        WB();
        // ---- coalesced val store (slot-ordered rows)
        {
            int row = lane >> 2, seg = lane & 3;
            int rw7 = row & 7;
            uint4 v0 = *(const uint4*)&scr_r[row * 64 + (((seg * 2) ^ rw7) << 3)];
            uint4 v1 = *(const uint4*)&scr_r[row * 64 + (((seg * 2 + 1) ^ rw7) << 3)];
            uint4* gp = (uint4*)&valbuf[(size_t)(e0 + row) * C + seg * 16];
            gp[0] = v0; gp[1] = v1;
        }
        WB();
        // ---- rotate
        t = tn; e = eN; s = sN; dd = ddN;
    }
}

// ================= aggregate: packed 2-channel/lane, 2 slots/wave, 2 chains =========
// Lane l: channels {2h, 2h+1} (h = l&31, same head h>>2); lanes 0-31 even slots,
// 32-63 odd slots. 256B contiguous valbuf per 2 slots. -1e30 sentinel (no NaN paths).
__global__ void aggregate_kernel(const int* __restrict__ row_ptr,
                                 const float* __restrict__ logitsbuf,
                                 const u16* __restrict__ valbuf,
                                 float* __restrict__ attout) {
    const int wave = threadIdx.x >> 6, lane = threadIdx.x & 63;
    const int h = lane & 31;
    const int parity = lane >> 5;
    const int head = h >> 2;
    const int gw = blockIdx.x * 4 + wave, nw = gridDim.x * 4;
    const float NINF = -1e30f;
    for (int d = gw; d < ND_N; d += nw) {
        const int beg = row_ptr[d], end = row_ptr[d + 1];
        float m0 = NINF, z0 = 0.f, a00 = 0.f, a01 = 0.f;
        float m1 = NINF, z1 = 0.f, a10 = 0.f, a11 = 0.f;
        for (int i = beg + parity; i < end; i += 4) {
            u32 pv = *(const u32*)&valbuf[(size_t)i * C + 2 * h];
            float lg = logitsbuf[(size_t)i * NH + head];
            float mn = fmaxf(m0, lg);
            float sc = __expf(m0 - mn);
            float e = __expf(lg - mn);
            z0 = z0 * sc + e;
            a00 = a00 * sc + e * lo16(pv);
            a01 = a01 * sc + e * hi16(pv);
            m0 = mn;
        }
        for (int i = beg + parity + 2; i < end; i += 4) {
            u32 pv = *(const u32*)&valbuf[(size_t)i * C + 2 * h];
            float lg = logitsbuf[(size_t)i * NH + head];
            float mn = fmaxf(m1, lg);
            float sc = __expf(m1 - mn);
            float e = __expf(lg - mn);
            z1 = z1 * sc + e;
            a10 = a10 * sc + e * lo16(pv);
            a11 = a11 * sc + e * hi16(pv);
            m1 = mn;
        }
        // merge the two chains (z's are 0 for empty chains; exp stays finite)
        float ma = fmaxf(m0, m1);
        float s0 = __expf(m0 - ma), s1 = __expf(m1 - ma);
        float z = z0 * s0 + z1 * s1;
        float a0 = a00 * s0 + a10 * s1;
        float a1 = a01 * s0 + a11 * s1;
        // merge halves (parity 0 <-> 1) via xor 32
        float mo = __shfl_xor(ma, 32, 64);
        float zo = __shfl_xor(z, 32, 64);
        float b0 = __shfl_xor(a0, 32, 64);
        float b1 = __shfl_xor(a1, 32, 64);
        float mm = fmaxf(ma, mo);
        float se = __expf(ma - mm), so = __expf(mo - mm);
        z = z * se + zo * so;
        a0 = a0 * se + b0 * so;
        a1 = a1 * se + b1 * so;
        if (parity == 0) {
            float2 r;
            r.x = (z > 0.f) ? a0 / z : 0.f;
            r.y = (z > 0.f) ? a1 / z : 0.f;
            *(float2*)&attout[(size_t)d * C + 2 * h] = r;
        }
    }
}

// ================= SLOW PATH edge kernel (fallback; bf16 ms/md) =====================
__global__ void edge_csr_kernel(const void* __restrict__ edge_attr,
                                const void* __restrict__ edge_scalars,
                                const void* __restrict__ edge_logits,
                                const int* __restrict__ edge_src,
                                const int* __restrict__ row_ptr, const int* __restrict__ perm,
                                const void* __restrict__ W_ea, const void* __restrict__ W_dtp,
                                const void* __restrict__ W_r1, const void* __restrict__ b_r1,
                                const void* __restrict__ W_r2, const void* __restrict__ b_r2,
                                const void* __restrict__ alpha_vec,
                                const int* __restrict__ flagp,
                                const u16* __restrict__ ms, const u16* __restrict__ md,
                                float* __restrict__ attout) {
    __shared__ u16 sWr1[SD * SD];
    __shared__ u16 sWr2[SD * 2 * C];
    __shared__ u16 sWdtp[C * 2 * C];
    __shared__ u16 sWea[AD * C];
    __shared__ float sbr1[SD], sbr2[2 * C], salpha[C];
    __shared__ float sbuf[4][2][C];

    const int isbf = *flagp;
    const int tid = threadIdx.x;
    {
        for (int i = tid; i < SD * SD; i += blockDim.x) {
            int k = i >> 6, c = i & 63;
            sWr1[((k >> 1) << 7) + (c << 1) + (k & 1)] = loadb(W_r1, i, isbf);
        }
        for (int i = tid; i < SD * 2 * C; i += blockDim.x) {
            int k = i >> 7, c = i & 127;
            sWr2[(k << 7) + ((c & 63) << 1) + (c >> 6)] = loadb(W_r2, i, isbf);
        }
        for (int i = tid; i < C * 2 * C; i += blockDim.x) {
            int k = i >> 7, c = i & 127;
            sWdtp[(k << 7) + ((c & 63) << 1) + (c >> 6)] = loadb(W_dtp, i, isbf);
        }
        for (int i = tid; i < AD * C; i += blockDim.x) {
            int k = i >> 6, c = i & 63;
            sWea[((k >> 1) << 7) + (c << 1) + (k & 1)] = loadb(W_ea, i, isbf);
        }
        for (int i = tid; i < SD; i += blockDim.x) sbr1[i] = loadf(b_r1, i, isbf);
        for (int i = tid; i < 2 * C; i += blockDim.x) sbr2[i] = loadf(b_r2, i, isbf);
        for (int i = tid; i < C; i += blockDim.x) salpha[i] = loadf(alpha_vec, i, isbf);
    }
    __syncthreads();

    const int wave = tid >> 6, lane = tid & 63;
    float* buf0 = sbuf[wave][0];
    float* buf1 = sbuf[wave][1];
    const u32* wr1 = (const u32*)sWr1;
    const u32* wr2 = (const u32*)sWr2;
    const u32* wdtp = (const u32*)sWdtp;
    const u32* wea = (const u32*)sWea;
    const int gw = blockIdx.x * 4 + wave, nw = gridDim.x * 4;

    for (int d = gw; d < ND_N; d += nw) {
        const int beg = row_ptr[d], end = row_ptr[d + 1];
        const float mdv = b2fu(md[(size_t)d * C + lane]);
        float m = -__builtin_inff(), z = 0.f, acc = 0.f;

        for (int i = beg; i < end; ++i) {
            const int e = perm[i];
            WB();
            buf0[lane] = loadf(edge_scalars, (size_t)e * SD + lane, isbf);
            WB();
            float accr = sbr1[lane];
            #pragma unroll 8
            for (int k2 = 0; k2 < 32; ++k2) {
                float2 xv = *(const float2*)&buf0[k2 * 2];
                u32 wp = wr1[(k2 << 6) + lane];
                accr += xv.x * lo16(wp) + xv.y * hi16(wp);
            }
            float r = accr / (1.f + __expf(-accr));
            WB();
            buf1[lane] = r;
            WB();
            float we0 = sbr2[lane], we1 = sbr2[lane + C];
            #pragma unroll 8
            for (int k = 0; k < SD; ++k) {
                float rk = buf1[k];
                u32 wp = wr2[(k << 6) + lane];
                we0 += rk * lo16(wp);
                we1 += rk * hi16(wp);
            }
            WB();
            if (lane < AD) buf0[lane] = loadf(edge_attr, (size_t)e * AD + lane, isbf);
            WB();
            float eav = 0.f;
            #pragma unroll
            for (int k2 = 0; k2 < 8; ++k2) {
                float2 xv = *(const float2*)&buf0[k2 * 2];
                u32 wp = wea[(k2 << 6) + lane];
                eav += xv.x * lo16(wp) + xv.y * hi16(wp);
            }
            const int s = edge_src[e];
            float x = (b2fu(ms[(size_t)s * C + lane]) + mdv) * eav;
            WB();
            buf1[lane] = x;
            WB();
            float dt0 = 0.f, dt1 = 0.f;
            #pragma unroll 8
            for (int k = 0; k < C; ++k) {
                float xk = buf1[k];
                u32 wp = wdtp[(k << 6) + lane];
                dt0 += xk * lo16(wp);
                dt1 += xk * hi16(wp);
            }
            dt0 *= we0;
            dt1 *= we1;
            float lf = (dt0 >= 0.f) ? dt0 : 0.2f * dt0;
            float t = lf * salpha[lane];
            t += __shfl_xor(t, 1, 64);
            t += __shfl_xor(t, 2, 64);
            t += __shfl_xor(t, 4, 64);
            float lg = t + loadf(edge_logits, e, isbf);
            float mn = fmaxf(m, lg);
            float sc = __expf(m - mn);
            float a = __expf(lg - mn);
            z = z * sc + a;
            acc = acc * sc + a * dt1;
            m = mn;
        }
        attout[(size_t)d * C + lane] = (z > 0.f) ? acc / z : 0.f;
    }
}

// ================= FAST PATH final: MFMA epilogue (16 nodes / wave-tile) ============
// 8-wave blocks: weights shared by 8 waves, 1 block/CU but 8 waves/CU.
__launch_bounds__(512, 2)
__global__ void final_mfma_kernel(const void* __restrict__ dst_f,
                                  const float* __restrict__ attout,
                                  const void* __restrict__ W_proj, const void* __restrict__ b_proj,
                                  const void* __restrict__ ln_w, const void* __restrict__ ln_b,
                                  const void* __restrict__ W_f1, const void* __restrict__ b_f1,
                                  const void* __restrict__ W_f2, const void* __restrict__ b_f2,
                                  const int* __restrict__ flagp,
                                  void* __restrict__ out) {
    // XOR-swizzled weight rows (group g of row n at g^(n&7))
    __shared__ u16 sWpT[C * C];         // 8 KB   [n=64][k=64]
    __shared__ u16 sWf1T[MF * C];       // 24 KB  [n=192][k=64]
    __shared__ u16 sWf2T[C * MF];       // 24 KB  [n=64][k=192]
    __shared__ float sbp[C], slnw[C], slnb[C], sbf1[MF], sbf2[C];
    __shared__ uint4 scr4[8][400];      // 6400 B per wave, phase-aliased scratch

    const int isbf = *flagp;
    const int tid = threadIdx.x;       // blockDim = 512 (8 waves)
    for (int i = tid; i < C * C; i += 512) {
        int k = i >> 6, n = i & 63;
        sWpT[n * 64 + (((k >> 3) ^ (n & 7)) << 3) + (k & 7)] = loadb(W_proj, i, isbf);
    }
    for (int i = tid; i < C * MF; i += 512) {
        int k = i / MF, n = i - k * MF;     // W_f1[k][n], n<192
        sWf1T[n * 64 + (((k >> 3) ^ (n & 7)) << 3) + (k & 7)] = loadb(W_f1, i, isbf);
    }
    for (int i = tid; i < MF * C; i += 512) {
        int k = i >> 6, n = i & 63;         // W_f2[k][n], k<192
        sWf2T[n * 192 + (((k >> 3) ^ (n & 7)) << 3) + (k & 7)] = loadb(W_f2, i, isbf);
    }
    for (int i = tid; i < C; i += 512) {
        sbp[i] = loadf(b_proj, i, isbf);
        slnw[i] = loadf(ln_w, i, isbf);
        slnb[i] = loadf(ln_b, i, isbf);
        sbf2[i] = loadf(b_f2, i, isbf);
    }
    for (int i = tid; i < MF; i += 512) sbf1[i] = loadf(b_f1, i, isbf);
    __syncthreads();

    const int wv = tid >> 6, lane = tid & 63;
    const int m15 = lane & 15, quad = lane >> 4;
    const int sw = m15 & 7;
    const int pg0 = (quad ^ sw) << 3;
    const int pg1 = pg0 ^ 32;
    u16* scr = (u16*)scr4[wv];
    float* scrf = (float*)scr4[wv];

    for (int t = blockIdx.x * 8 + wv; t < ND_N / 16; t += gridDim.x * 8) {
        const int n0 = t * 16;
        short8 oA0 = load8bf(attout, (size_t)(n0 + m15) * C + quad * 8, 0);
        short8 oA1 = load8bf(attout, (size_t)(n0 + m15) * C + 32 + quad * 8, 0);
        float emb[4][4];
        #pragma unroll
        for (int nt = 0; nt < 4; ++nt) {
            f32x4 c = {0.f, 0.f, 0.f, 0.f};
            c = MFMA16(oA0, *(const short8*)&sWpT[(nt * 16 + m15) * 64 + pg0], c);
            c = MFMA16(oA1, *(const short8*)&sWpT[(nt * 16 + m15) * 64 + pg1], c);
            int col = nt * 16 + m15;
            float bp = sbp[col];
            #pragma unroll
            for (int r = 0; r < 4; ++r)
                emb[nt][r] = c[r] + bp + loadf(dst_f, (size_t)(n0 + quad * 4 + r) * C + col, isbf);
        }
        float y[4][4];
        #pragma unroll
        for (int r = 0; r < 4; ++r) {
            float part = emb[0][r] + emb[1][r] + emb[2][r] + emb[3][r];
            part += __shfl_xor(part, 1, 64);
            part += __shfl_xor(part, 2, 64);
            part += __shfl_xor(part, 4, 64);
            part += __shfl_xor(part, 8, 64);
            float mean = part * (1.f / 64.f);
            float q = 0.f;
            #pragma unroll
            for (int nt = 0; nt < 4; ++nt) {
                float d = emb[nt][r] - mean;
                q += d * d;
            }
            q += __shfl_xor(q, 1, 64);
            q += __shfl_xor(q, 2, 64);
            q += __shfl_xor(q, 4, 64);
            q += __shfl_xor(q, 8, 64);
            float rs = rsqrtf(q * (1.f / 64.f) + EPSV);
            #pragma unroll
            for (int nt = 0; nt < 4; ++nt) {
                int col = nt * 16 + m15;
                y[nt][r] = (emb[nt][r] - mean) * rs * slnw[col] + slnb[col];
            }
        }
        WB();
        #pragma unroll
        for (int nt = 0; nt < 4; ++nt)
            #pragma unroll
            for (int r = 0; r < 4; ++r)
                scr[(quad * 4 + r) * 72 + nt * 16 + m15] = f2bbits(y[nt][r]);
        WB();
        short8 yA0 = *(const short8*)&scr[m15 * 72 + quad * 8];
        short8 yA1 = *(const short8*)&scr[m15 * 72 + 32 + quad * 8];
        WB();
        #pragma unroll
        for (int nt = 0; nt < 12; ++nt) {
            f32x4 g = {0.f, 0.f, 0.f, 0.f};
            g = MFMA16(yA0, *(const short8*)&sWf1T[(nt * 16 + m15) * 64 + pg0], g);
            g = MFMA16(yA1, *(const short8*)&sWf1T[(nt * 16 + m15) * 64 + pg1], g);
            int col = nt * 16 + m15;
            float bg = sbf1[col];
            #pragma unroll
            for (int r = 0; r < 4; ++r) {
                float f = g[r] + bg;
                f = f / (1.f + __expf(-f));
                scr[(quad * 4 + r) * 200 + col] = f2bbits(f);
            }
        }
        WB();
        short8 gA[6];
        #pragma unroll
        for (int j = 0; j < 6; ++j)
            gA[j] = *(const short8*)&scr[m15 * 200 + j * 32 + quad * 8];
        WB();
        #pragma unroll
        for (int nt = 0; nt < 4; ++nt) {
            f32x4 c = {0.f, 0.f, 0.f, 0.f};
            #pragma unroll
            for (int j = 0; j < 6; ++j) {
                int lg = j * 4 + quad;           // logical group in 24-group row
                int pg = (lg ^ sw) << 3;         // n&7 = m15&7 = sw
                c = MFMA16(gA[j], *(const short8*)&sWf2T[(nt * 16 + m15) * 192 + pg], c);
            }
            int col = nt * 16 + m15;
            float bf = sbf2[col];
            #pragma unroll
            for (int r = 0; r < 4; ++r)
                scrf[(quad * 4 + r) * 68 + col] = c[r] + bf + emb[nt][r];
        }
        WB();
        {
            int row = lane >> 2, seg = lane & 3;
            if (isbf) {
                u16* gp = (u16*)out + (size_t)(n0 + row) * C + seg * 16;
                #pragma unroll
                for (int j = 0; j < 4; ++j) {
                    float4 v = *(const float4*)&scrf[row * 68 + seg * 16 + j * 4];
                    u32 p0 = (u32)f2bbits(v.x) | ((u32)f2bbits(v.y) << 16);
                    u32 p1 = (u32)f2bbits(v.z) | ((u32)f2bbits(v.w) << 16);
                    uint2 pk = {p0, p1};
                    *(uint2*)(gp + j * 4) = pk;
                }
            } else {
                float* gp = (float*)out + (size_t)(n0 + row) * C + seg * 16;
                #pragma unroll
                for (int j = 0; j < 4; ++j)
                    *(float4*)(gp + j * 4) = *(const float4*)&scrf[row * 68 + seg * 16 + j * 4];
            }
        }
        WB();
    }
}

// ================= SLOW PATH final (scalar) ========================================
__global__ void final_scalar_kernel(const void* __restrict__ dst_f,
                                    const float* __restrict__ attout,
                                    const void* __restrict__ W_proj, const void* __restrict__ b_proj,
                                    const void* __restrict__ ln_w, const void* __restrict__ ln_b,
                                    const void* __restrict__ W_f1, const void* __restrict__ b_f1,
                                    const void* __restrict__ W_f2, const void* __restrict__ b_f2,
                                    const int* __restrict__ flagp,
                                    void* __restrict__ out) {
    __shared__ u16 sWp[C * C];
    __shared__ u16 sWf1p[C * 2 * C];
    __shared__ u16 sWf1c[C * C];
    __shared__ u16 sWf2[MF * C];
    __shared__ float sbp[C], slnw[C], slnb[C], sbf1[MF], sbf2[C];
    __shared__ float ybuf[4][C];
    __shared__ float gbuf[4][MF];

    const int isbf = *flagp;
    const int tid = threadIdx.x;
    {
        for (int i = tid; i < C * C; i += blockDim.x) {
            int k = i >> 6, c = i & 63;
            sWp[((k >> 1) << 7) + (c << 1) + (k & 1)] = loadb(W_proj, i, isbf);
        }
        for (int i = tid; i < C * MF; i += blockDim.x) {
            int k = i / MF, c = i - k * MF;
            u16 b = loadb(W_f1, i, isbf);
            if (c < 128) sWf1p[(k << 7) + ((c & 63) << 1) + (c >> 6)] = b;
            else         sWf1c[(k << 6) + (c - 128)] = b;
        }
        for (int i = tid; i < MF * C; i += blockDim.x) {
            int k = i >> 6, c = i & 63;
            sWf2[((k >> 1) << 7) + (c << 1) + (k & 1)] = loadb(W_f2, i, isbf);
        }
        for (int i = tid; i < C; i += blockDim.x) {
            sbp[i] = loadf(b_proj, i, isbf);
            slnw[i] = loadf(ln_w, i, isbf);
            slnb[i] = loadf(ln_b, i, isbf);
            sbf2[i] = loadf(b_f2, i, isbf);
        }
        for (int i = tid; i < MF; i += blockDim.x) sbf1[i] = loadf(b_f1, i, isbf);
    }
    __syncthreads();

    const int wave = tid >> 6, lane = tid & 63;
    const u32* wp32 = (const u32*)sWp;
    const u32* wf1 = (const u32*)sWf1p;
    const u32* wf2 = (const u32*)sWf2;
    const int gw = blockIdx.x * 4 + wave, nw = gridDim.x * 4;

    for (int n = gw; n < ND_N; n += nw) {
        float o = attout[(size_t)n * C + lane];
        WB();
        ybuf[wave][lane] = o;
        WB();
        float p = sbp[lane];
        #pragma unroll 8
        for (int k2 = 0; k2 < 32; ++k2) {
            float2 yv = *(const float2*)&ybuf[wave][k2 * 2];
            u32 wv = wp32[(k2 << 6) + lane];
            p += yv.x * lo16(wv) + yv.y * hi16(wv);
        }
        float emb = p + loadf(dst_f, (size_t)n * C + lane, isbf);
        float mean = waveAllSum(emb) * (1.f / 64.f);
        float ec = emb - mean;
        float var = waveAllSum(ec * ec) * (1.f / 64.f);
        float y = ec * rsqrtf(var + EPSV) * slnw[lane] + slnb[lane];
        WB();
        ybuf[wave][lane] = y;
        WB();
        float g0 = sbf1[lane], g1v = sbf1[lane + C], g2v = sbf1[lane + 2 * C];
        #pragma unroll 8
        for (int k = 0; k < C; ++k) {
            float yk = ybuf[wave][k];
            u32 wv = wf1[(k << 6) + lane];
            union { u32 u; float f; } cv; cv.u = ((u32)sWf1c[(k << 6) + lane]) << 16;
            g0 += yk * lo16(wv);
            g1v += yk * hi16(wv);
            g2v += yk * cv.f;
        }
        WB();
        gbuf[wave][lane] = g0 / (1.f + __expf(-g0));
        gbuf[wave][lane + C] = g1v / (1.f + __expf(-g1v));
        gbuf[wave][lane + 2 * C] = g2v / (1.f + __expf(-g2v));
        WB();
        float f = sbf2[lane];
        #pragma unroll 8
        for (int k2 = 0; k2 < 96; ++k2) {
            float2 gv = *(const float2*)&gbuf[wave][k2 * 2];
            u32 wv = wf2[(k2 << 6) + lane];
            f += gv.x * lo16(wv) + gv.y * hi16(wv);
        }
        WB();
        float res = f + emb;
        if (isbf) ((bf16*)out)[(size_t)n * C + lane] = __float2bfloat16(res);
        else      ((float*)out)[(size_t)n * C + lane] = res;
    }
}

extern "C" void kernel_launch(void* const* d_in, const int* in_sizes, int n_in,
                              void* d_out, int out_size, void* d_ws, size_t ws_size,
                              hipStream_t stream) {
    const void* src_f        = d_in[0];
    const void* dst_f        = d_in[1];
    const void* edge_attr    = d_in[2];
    const void* edge_scalars = d_in[3];
    const void* edge_logits  = d_in[4];
    const int*  edge_src     = (const int*)d_in[5];
    const int*  edge_dst     = (const int*)d_in[6];
    const void* ln_src_w = d_in[7];
    const void* ln_src_b = d_in[8];
    const void* W_src    = d_in[9];
    const void* ln_dst_w = d_in[10];
    const void* ln_dst_b = d_in[11];
    const void* W_dst    = d_in[12];
    const void* b_dst    = d_in[13];
    const void* W_ea     = d_in[14];
    const void* W_dtp    = d_in[15];
    const void* W_r1     = d_in[16];
    const void* b_r1     = d_in[17];
    const void* W_r2     = d_in[18];
    const void* b_r2     = d_in[19];
    const void* alpha_vec = d_in[20];
    const void* W_proj   = d_in[21];
    const void* b_proj   = d_in[22];
    const void* ln_post_w = d_in[23];
    const void* ln_post_b = d_in[24];
    const void* W_f1     = d_in[25];
    const void* b_f1     = d_in[26];
    const void* W_f2     = d_in[27];
    const void* b_f2     = d_in[28];

    // ---- workspace layout (ms/md regions sized for fp32 but hold bf16 content;
    //      ms region reused as fp32 attout after the edge kernel) ----
    int* flag     = (int*)d_ws;                         // 16 ints
    float* msf    = (float*)d_ws + 16;                  // NS*C fp32-sized region
    float* mdf    = msf + (size_t)NS_N * C;             // ND*C fp32-sized region
    u16* ms16     = (u16*)msf;
    u16* md16     = (u16*)mdf;
    int* cnt      = (int*)(mdf + (size_t)ND_N * C);     // ND
    int* row_ptr  = cnt + ND_N;                         // ND+1 (padded)
    int* cursor   = row_ptr + (ND_N + 4);               // ND
    int* perm     = cursor + ND_N;                      // E
    float* logitsbuf = (float*)(perm + NE_E);           // fast: E*NH (slot-indexed)
    u16* valbuf      = (u16*)(logitsbuf + (size_t)NE_E * NH); // fast: E*C bf16 (slot-indexed)
    float* attout_slow = (float*)(perm + NE_E);         // slow: ND*C (aliases logitsbuf)

    size_t base_b = (size_t)(16 + NS_N * C + ND_N * C) * 4
                  + ((size_t)ND_N * 3 + 4 + NE_E) * 4;
    size_t need_fast = base_b + (size_t)NE_E * NH * 4 + (size_t)NE_E * C * 2;
    size_t need_slow = base_b + (size_t)ND_N * C * 4;
    int fast = (ws_size >= need_fast) ? 1 : 0;
    if (!fast && ws_size < need_slow) return;

    // detect + cnt-zero fused
    detect_zero_kernel<<<1 + (ND_N + 255) / 256, 256, 0, stream>>>(src_f, flag, cnt);
    hist_kernel<<<(NE_E + 255) / 256, 256, 0, stream>>>(edge_dst, cnt);
    scan_phase1<<<SCAN_NCH, 256, 0, stream>>>(cnt, perm);
    scan_phase3<<<SCAN_NCH, 256, 0, stream>>>(cnt, perm, row_ptr, cursor, &row_ptr[ND_N]);
    scatter_kernel<<<(NE_E + 255) / 256, 256, 0, stream>>>(edge_dst, cursor, perm);

    // fused dual node projection (MFMA, bf16 outputs); 782*8 waves ~ 6250 tiles
    node_proj2_mfma<<<782, 512, 0, stream>>>(src_f, dst_f,
                                             ln_src_w, ln_src_b, W_src,
                                             ln_dst_w, ln_dst_b, W_dst, b_dst,
                                             flag, ms16, md16);

    if (fast) {
        edge_mfma_kernel<<<1024, 512, 0, stream>>>(edge_attr, edge_scalars, edge_logits,
                                                   edge_src, edge_dst, perm,
                                                   W_ea, W_dtp, W_r1, b_r1, W_r2, b_r2,
                                                   alpha_vec, flag, ms16, md16,
                                                   valbuf, logitsbuf);
        // ms region dead after edge kernel -> reuse as fp32 attout
        aggregate_kernel<<<4096, 256, 0, stream>>>(row_ptr, logitsbuf, valbuf, msf);
        final_mfma_kernel<<<256, 512, 0, stream>>>(dst_f, msf,
                                                   W_proj, b_proj, ln_post_w, ln_post_b,
                                                   W_f1, b_f1, W_f2, b_f2,
                                                   flag, d_out);
    } else {
        edge_csr_kernel<<<2048, 256, 0, stream>>>(edge_attr, edge_scalars, edge_logits,
                                                  edge_src, row_ptr, perm,
                                                  W_ea, W_dtp, W_r1, b_r1, W_r2, b_r2,
                                                  alpha_vec, flag, ms16, md16, attout_slow);
        final_scalar_kernel<<<1024, 256, 0, stream>>>(dst_f, attout_slow,
                                                      W_proj, b_proj, ln_post_w, ln_post_b,
                                                      W_f1, b_f1, W_f2, b_f2,
                                                      flag, d_out);
    }
}